// Round 15
// baseline (176.083 us; speedup 1.0000x reference)
//
#include <hip/hip_runtime.h>
#include <hip/hip_bf16.h>

// ---------------------------------------------------------------------------
// Round 14 = R13 (passing, 168.1us) + dataflow elimination around frozen core:
//  - xb intermediate removed: k_proj packs x f32->bf16 during reg staging
//    (identical f2bf RNE rounding); k_conv now only converts weights (1088 blk)
//  - k_mlp1+k_mlp2 fused (same-block h1 dependency): h1 bf16 kept in the as_
//    LDS buffer, W2 reloaded into the w1 buffer; h1 global round-trip deleted
//  - 7 -> 6 launches. k_z / k_zred / k_av byte-exact R13 (FROZEN).
// ---------------------------------------------------------------------------

typedef __bf16 bf16x8 __attribute__((ext_vector_type(8)));
typedef float f32x4 __attribute__((ext_vector_type(4)));

constexpr float SCALEc = 1.0f / 11.0f;  // int(sqrt(128)) == 11 (faithful)
constexpr float EPSc = 1e-5f;

#define MFMA(a, b, c) __builtin_amdgcn_mfma_f32_16x16x32_bf16(a, b, c, 0, 0, 0)

static __device__ __forceinline__ unsigned short f2bf(float f) {
  unsigned int x = __float_as_uint(f);
  x += 0x7fffu + ((x >> 16) & 1u);  // RNE
  return (unsigned short)(x >> 16);
}
static __device__ __forceinline__ unsigned int pack2(float a, float b) {
  return (unsigned int)f2bf(a) | ((unsigned int)f2bf(b) << 16);
}
static __device__ __forceinline__ float red16(float v) {
  v += __shfl_xor(v, 1); v += __shfl_xor(v, 2);
  v += __shfl_xor(v, 4); v += __shfl_xor(v, 8);
  return v;
}
// async 16B global->LDS (LDS dest = wave-uniform base + lane*16, linear)
static __device__ __forceinline__ void gl_lds16(const void* g, void* l) {
  __builtin_amdgcn_global_load_lds(
      (const __attribute__((address_space(1))) void*)g,
      (__attribute__((address_space(3))) void*)l, 16, 0, 0);
}

// ---------------------------------------------------------------------------
// Weight converts only (xb eliminated). grid 1088 x 256.
// ---------------------------------------------------------------------------
__global__ __launch_bounds__(256) void k_conv(
    const float* __restrict__ Wq, const float* __restrict__ Wk,
    const float* __restrict__ Wv, const float* __restrict__ W1,
    const float* __restrict__ W2, unsigned short* __restrict__ Wt) {
  int t = blockIdx.x * 256 + threadIdx.x;
  if (t < 196608) {
    int which = t >> 16, r = t & 65535;
    int h = r >> 14, idx = r & 16383;
    int d = idx >> 7, e = idx & 127;
    const float* W = which == 0 ? Wq : (which == 1 ? Wk : Wv);
    Wt[t] = f2bf(W[h * 16384 + e * 128 + d]);
  } else if (t < 262144) {
    int r = t - 196608, d = r >> 9, k = r & 511;
    Wt[t] = f2bf(W1[k * 128 + d]);
  } else if (t < 278528) {
    int r = t - 262144, d = r >> 7, k = r & 127;
    Wt[t] = f2bf(W2[k * 128 + d]);
  }
}

// ---------------------------------------------------------------------------
// Fused projections reading x f32 directly (pack to bf16 while staging).
// grid (256, 12): y<8 -> Q/K proj+LN; y>=8 -> V proj transposed.
// ---------------------------------------------------------------------------
__global__ __launch_bounds__(256, 2) void k_proj(
    const float* __restrict__ xg, const unsigned short* __restrict__ Wt,
    const float* __restrict__ bq, const float* __restrict__ bk,
    const float* __restrict__ bv, unsigned short* __restrict__ Qw,
    unsigned short* __restrict__ Kw, unsigned short* __restrict__ Vtw) {
  __shared__ unsigned short xs[128][136];
  __shared__ unsigned short wt[128][136];
  const int tid = threadIdx.x;
  const int wid = tid >> 6, lane = tid & 63, lr = lane & 15, lg = lane >> 4;

  if (blockIdx.y < 8) {
    const int proj = blockIdx.y >> 2, h = blockIdx.y & 3;
    const int r0 = blockIdx.x * 128;
    const unsigned short* wsrc = Wt + proj * 65536 + h * 16384;
    const float* bias = (proj == 0 ? bq : bk) + h * 128;
    unsigned short* dst =
        (proj == 0 ? Qw : Kw) + ((size_t)((r0 >> 9) * 4 + h) * 512 + (r0 & 511)) * 128;

#pragma unroll
    for (int i = 0; i < 8; ++i) {
      int f = tid + i * 256, row = f >> 4, c8 = (f & 15) * 8;
      const float* xp = xg + (size_t)(r0 + row) * 128 + c8;
      float4 a = *(const float4*)xp;
      float4 b2 = *(const float4*)(xp + 4);
      uint4 o;
      o.x = pack2(a.x, a.y); o.y = pack2(a.z, a.w);
      o.z = pack2(b2.x, b2.y); o.w = pack2(b2.z, b2.w);
      *(uint4*)&xs[row][c8] = o;
      *(uint4*)&wt[row][c8] = *(const uint4*)(wsrc + row * 128 + c8);
    }
    __syncthreads();

    const int wr0 = wid * 32;
    f32x4 acc[2][8];
#pragma unroll
    for (int i = 0; i < 2; ++i)
#pragma unroll
      for (int j = 0; j < 8; ++j) acc[i][j] = (f32x4)0.f;

    __builtin_amdgcn_s_setprio(1);
#pragma unroll
    for (int ksi = 0; ksi < 4; ++ksi) {
      const int k0 = ksi * 32 + lg * 8;
      bf16x8 af0 = *(const bf16x8*)&xs[wr0 + lr][k0];
      bf16x8 af1 = *(const bf16x8*)&xs[wr0 + 16 + lr][k0];
#pragma unroll
      for (int fj = 0; fj < 8; ++fj) {
        bf16x8 bfr = *(const bf16x8*)&wt[fj * 16 + lr][k0];
        acc[0][fj] = MFMA(af0, bfr, acc[0][fj]);
        acc[1][fj] = MFMA(af1, bfr, acc[1][fj]);
      }
    }
    __builtin_amdgcn_s_setprio(0);

    float bb[8];
#pragma unroll
    for (int fj = 0; fj < 8; ++fj) bb[fj] = bias[fj * 16 + lr];
#pragma unroll
    for (int fi = 0; fi < 2; ++fi)
#pragma unroll
      for (int r = 0; r < 4; ++r) {
        const int row = wr0 + fi * 16 + lg * 4 + r;
        float v[8], s = 0.f, s2 = 0.f;
#pragma unroll
        for (int fj = 0; fj < 8; ++fj) {
          v[fj] = acc[fi][fj][r] + bb[fj];
          s += v[fj]; s2 += v[fj] * v[fj];
        }
        s = red16(s); s2 = red16(s2);
        const float mu = s * (1.f / 128.f);
        const float inv = rsqrtf(s2 * (1.f / 128.f) - mu * mu + EPSc);
#pragma unroll
        for (int fj = 0; fj < 8; ++fj)
          dst[(size_t)row * 128 + fj * 16 + lr] = f2bf((v[fj] - mu) * inv);
      }
    return;
  }

  // ---- V projection transposed (h = blockIdx.y - 8) ----
  const int h = blockIdx.y - 8;
  const int n0 = blockIdx.x * 128;
  const unsigned short* wsrc = Wt + 131072 + h * 16384;
#pragma unroll
  for (int i = 0; i < 8; ++i) {
    int f = tid + i * 256, row = f >> 4, c8 = (f & 15) * 8;
    const float* xp = xg + (size_t)(n0 + row) * 128 + c8;
    float4 a = *(const float4*)xp;
    float4 b2 = *(const float4*)(xp + 4);
    uint4 o;
    o.x = pack2(a.x, a.y); o.y = pack2(a.z, a.w);
    o.z = pack2(b2.x, b2.y); o.w = pack2(b2.z, b2.w);
    *(uint4*)&xs[row][c8] = o;
    *(uint4*)&wt[row][c8] = *(const uint4*)(wsrc + row * 128 + c8);
  }
  __syncthreads();
  const int wn0 = wid * 32;
  f32x4 acc[8][2];
#pragma unroll
  for (int i = 0; i < 8; ++i) {
    acc[i][0] = (f32x4)0.f; acc[i][1] = (f32x4)0.f;
  }
  __builtin_amdgcn_s_setprio(1);
#pragma unroll
  for (int ksi = 0; ksi < 4; ++ksi) {
    const int k0 = ksi * 32 + lg * 8;
    bf16x8 bf0 = *(const bf16x8*)&xs[wn0 + lr][k0];
    bf16x8 bf1 = *(const bf16x8*)&xs[wn0 + 16 + lr][k0];
#pragma unroll
    for (int fi = 0; fi < 8; ++fi) {
      bf16x8 af = *(const bf16x8*)&wt[fi * 16 + lr][k0];
      acc[fi][0] = MFMA(af, bf0, acc[fi][0]);
      acc[fi][1] = MFMA(af, bf1, acc[fi][1]);
    }
  }
  __builtin_amdgcn_s_setprio(0);
#pragma unroll
  for (int fi = 0; fi < 8; ++fi)
#pragma unroll
    for (int r = 0; r < 4; ++r) {
      const float bvv = bv[h * 128 + fi * 16 + lg * 4 + r];
      acc[fi][0][r] += bvv; acc[fi][1][r] += bvv;
    }
  const int gb = n0 >> 9;
  unsigned short* base = Vtw + (size_t)(gb * 4 + h) * 128 * 512;
#pragma unroll
  for (int fj = 0; fj < 2; ++fj) {
    float s = 0.f, s2 = 0.f;
#pragma unroll
    for (int fi = 0; fi < 8; ++fi)
#pragma unroll
      for (int r = 0; r < 4; ++r) {
        const float v = acc[fi][fj][r];
        s += v; s2 += v * v;
      }
    s += __shfl_xor(s, 16); s += __shfl_xor(s, 32);
    s2 += __shfl_xor(s2, 16); s2 += __shfl_xor(s2, 32);
    const float mu = s * (1.f / 128.f);
    const float inv = rsqrtf(s2 * (1.f / 128.f) - mu * mu + EPSc);
    const int nl = (n0 & 511) + wn0 + fj * 16 + lr;
#pragma unroll
    for (int fi = 0; fi < 8; ++fi)
#pragma unroll
      for (int r = 0; r < 4; ++r) {
        const int eout = fi * 16 + lg * 4 + r;
        base[(size_t)eout * 512 + nl] = f2bf((acc[fi][fj][r] - mu) * inv);
      }
  }
}

// ---------------------------------------------------------------------------
// Z partials: Zp[bs8,h,n,m] = sum_{8 b in group} exp(QK/11). grid 512 flat,
// XCD-swizzled (h fixed per class). Single-buffered 64KB LDS => 2 blocks/CU.
// Both-sides XOR swizzle + setprio. (R13-exact, FROZEN)
// ---------------------------------------------------------------------------
__global__ __launch_bounds__(256, 2) void k_z(
    const unsigned short* __restrict__ Qw, const unsigned short* __restrict__ Kw,
    float* __restrict__ Zp) {
  __shared__ __align__(16) unsigned short qs[128 * 128];
  __shared__ __align__(16) unsigned short ks_[128 * 128];
  const int tid = threadIdx.x;
  const int bid = blockIdx.x;
  const int c = bid & 7, s_ = bid >> 3;          // XCD class, sequence [0,64)
  const int combo = (s_ >> 4) * 8 + c;           // [0,32)
  const int h = combo & 3, bs8 = combo >> 2;     // h fixed per class
  const int t = s_ & 15;
  const int nt = t >> 2, mt = t & 3;
  const int wid = tid >> 6, lane = tid & 63, lr = lane & 15, lg = lane >> 4;
  const int srow = lane >> 4, ssub = lane & 15;  // staging role

  auto stageZ = [&](const unsigned short* qb, const unsigned short* kb) {
#pragma unroll
    for (int j = 0; j < 8; ++j) {
      const int cc = wid + 4 * j;                // 1KB chunk = 4 rows of 256B
      const int row = 4 * cc + srow;
      const int gof = row * 128 + ((ssub ^ (row & 7)) << 3);
      gl_lds16(qb + gof, &qs[cc * 512]);
      gl_lds16(kb + gof, &ks_[cc * 512]);
    }
  };

  f32x4 zacc[2][8];
#pragma unroll
  for (int i = 0; i < 2; ++i)
#pragma unroll
    for (int j = 0; j < 8; ++j) zacc[i][j] = (f32x4)0.f;

  const int b0 = bs8 * 8;
  for (int bi = 0; bi < 8; ++bi) {
    const int b = b0 + bi;
    stageZ(Qw + ((size_t)(b * 4 + h) * 512 + nt * 128) * 128,
           Kw + ((size_t)(b * 4 + h) * 512 + mt * 128) * 128);
    __syncthreads();  // vmcnt(0) drain: tiles ready
    f32x4 s[2][8];
#pragma unroll
    for (int i = 0; i < 2; ++i)
#pragma unroll
      for (int j = 0; j < 8; ++j) s[i][j] = (f32x4)0.f;
    __builtin_amdgcn_s_setprio(1);
#pragma unroll
    for (int ksi = 0; ksi < 4; ++ksi) {
      const int k0 = ksi * 32 + lg * 8;
      const int ra0 = wid * 32 + lr, ra1 = wid * 32 + 16 + lr;
      bf16x8 af0 = *(const bf16x8*)&qs[(ra0 * 128 + k0) ^ ((ra0 & 7) << 3)];
      bf16x8 af1 = *(const bf16x8*)&qs[(ra1 * 128 + k0) ^ ((ra1 & 7) << 3)];
#pragma unroll
      for (int fj = 0; fj < 8; ++fj) {
        const int rb = fj * 16 + lr;
        bf16x8 bfr = *(const bf16x8*)&ks_[(rb * 128 + k0) ^ ((rb & 7) << 3)];
        s[0][fj] = MFMA(af0, bfr, s[0][fj]);
        s[1][fj] = MFMA(af1, bfr, s[1][fj]);
      }
    }
    __builtin_amdgcn_s_setprio(0);
#pragma unroll
    for (int fi = 0; fi < 2; ++fi)
#pragma unroll
      for (int fj = 0; fj < 8; ++fj)
#pragma unroll
        for (int r = 0; r < 4; ++r)
          zacc[fi][fj][r] += __expf(s[fi][fj][r] * SCALEc);
    __syncthreads();  // all reads done -> next stage may overwrite
  }
#pragma unroll
  for (int fi = 0; fi < 2; ++fi)
#pragma unroll
    for (int r = 0; r < 4; ++r) {
      const int n = nt * 128 + wid * 32 + fi * 16 + lg * 4 + r;
      float* zp = Zp + (size_t)bs8 * 1048576 +
                  ((size_t)h * 512 + n) * 512 + mt * 128;
#pragma unroll
      for (int fj = 0; fj < 8; ++fj) zp[fj * 16 + lr] = zacc[fi][fj][r];
    }
}

// ---------------------------------------------------------------------------
// Lz = -ln(sum_{8 partials} Zp). grid 1024 x 256. (R13-exact)
// ---------------------------------------------------------------------------
__global__ __launch_bounds__(256) void k_zred(const float* __restrict__ Zp,
                                              float* __restrict__ Lz) {
  size_t i = ((size_t)blockIdx.x * 256 + threadIdx.x) * 4;
  float4 s = *(const float4*)(Zp + i);
#pragma unroll
  for (int p = 1; p < 8; ++p) {
    float4 t = *(const float4*)(Zp + (size_t)p * 1048576 + i);
    s.x += t.x; s.y += t.y; s.z += t.z; s.w += t.w;
  }
  float4 o = make_float4(-__logf(s.x), -__logf(s.y),
                         -__logf(s.z), -__logf(s.w));
  *(float4*)(Lz + i) = o;
}

// ---------------------------------------------------------------------------
// AV: A[b,h,n,e] = sum_m exp(QK/11 + Lz) * V -> Aw[b,n,h*128+e] bf16.
// grid 1024 flat, XCD-swizzled (h fixed per class). Q in registers;
// K/Vt async dbuf via global_load_lds + XOR; ps XOR-swizzled [128][64]
// => LDS 80KB => 2 blocks/CU. (R13-exact, FROZEN)
// ---------------------------------------------------------------------------
__global__ __launch_bounds__(256, 2) void k_av(
    const unsigned short* __restrict__ Qw, const unsigned short* __restrict__ Kw,
    const unsigned short* __restrict__ Vtw, const float* __restrict__ Lz,
    unsigned short* __restrict__ Aw) {
  __shared__ __align__(16) unsigned short kt[2][64 * 128];
  __shared__ __align__(16) unsigned short vt[2][128 * 64];
  __shared__ __align__(16) unsigned short ps[128 * 64];
  const int tid = threadIdx.x;
  const int bid = blockIdx.x;
  const int c = bid & 7, s_ = bid >> 3;
  const int g = s_ >> 2, nt = s_ & 3;
  const int bh = g * 8 + c;
  const int h = bh & 3, b = bh >> 2;
  const int wid = tid >> 6, lane = tid & 63, lr = lane & 15, lg = lane >> 4;

  const unsigned short* ksrc0 = Kw + (size_t)bh * 65536;
  const unsigned short* vsrc0 = Vtw + (size_t)bh * 65536;
  const unsigned short* qsrc = Qw + ((size_t)bh * 512 + nt * 128) * 128;

  auto stage = [&](int mt, int buf) {
    const unsigned short* kb = ksrc0 + (size_t)mt * 64 * 128;
#pragma unroll
    for (int j = 0; j < 4; ++j) {            // K tile: 64 rows x 256B
      const int cc = wid + 4 * j;
      const int row = 4 * cc + (lane >> 4), sub = lane & 15;
      gl_lds16(kb + row * 128 + ((sub ^ (row & 7)) << 3), &kt[buf][cc * 512]);
    }
    const unsigned short* vb = vsrc0 + mt * 64;
#pragma unroll
    for (int j = 0; j < 4; ++j) {            // Vt tile: 128 rows x 128B
      const int cc = wid + 4 * j;
      const int row = 8 * cc + (lane >> 3), sub = lane & 7;
      gl_lds16(vb + (size_t)row * 512 + ((sub ^ (row & 7)) << 3),
               &vt[buf][cc * 512]);
    }
  };

  stage(0, 0);
  // Q fragments -> registers (wave-private 32 rows)
  bf16x8 qreg[2][4];
#pragma unroll
  for (int pi = 0; pi < 2; ++pi)
#pragma unroll
    for (int ksi = 0; ksi < 4; ++ksi)
      qreg[pi][ksi] = *(const bf16x8*)(qsrc +
          (size_t)(wid * 32 + pi * 16 + lr) * 128 + ksi * 32 + lg * 8);
  __syncthreads();  // buf0 ready

  f32x4 acc[8][2];
#pragma unroll
  for (int i = 0; i < 8; ++i) { acc[i][0] = (f32x4)0.f; acc[i][1] = (f32x4)0.f; }
  const float* zbase = Lz + ((size_t)h * 512 + nt * 128) * 512;

  for (int mt = 0; mt < 8; ++mt) {
    const int cur = mt & 1;
    if (mt < 7) stage(mt + 1, cur ^ 1);
    // Lz for this tile (L2-resident per XCD class)
    float zr[2][4][4];
#pragma unroll
    for (int pi = 0; pi < 2; ++pi)
#pragma unroll
      for (int fm = 0; fm < 4; ++fm)
#pragma unroll
        for (int r = 0; r < 4; ++r)
          zr[pi][fm][r] = zbase[(size_t)(wid * 32 + pi * 16 + lg * 4 + r) * 512 +
                                mt * 64 + fm * 16 + lr];
    // S = Q K^T (32n x 64m per wave)
    f32x4 s[2][4];
#pragma unroll
    for (int i = 0; i < 2; ++i)
#pragma unroll
      for (int j = 0; j < 4; ++j) s[i][j] = (f32x4)0.f;
    __builtin_amdgcn_s_setprio(1);
#pragma unroll
    for (int ksi = 0; ksi < 4; ++ksi) {
      const int k0 = ksi * 32 + lg * 8;
#pragma unroll
      for (int fm = 0; fm < 4; ++fm) {
        const int row = fm * 16 + lr;
        bf16x8 bfr = *(const bf16x8*)&kt[cur][(row * 128 + k0) ^ ((row & 7) << 3)];
        s[0][fm] = MFMA(qreg[0][ksi], bfr, s[0][fm]);
        s[1][fm] = MFMA(qreg[1][ksi], bfr, s[1][fm]);
      }
    }
    __builtin_amdgcn_s_setprio(0);
    // P = exp(s/11 + lz) -> bf16 via cvt_pk -> ps (wave-private rows).
    // ps XOR layout: idx(n,m) = n*64 + (((m>>3)^(n&7))<<3) + (m&7).
#pragma unroll
    for (int pi = 0; pi < 2; ++pi)
#pragma unroll
      for (int fm = 0; fm < 4; ++fm) {
        const int m = fm * 16 + lr;
        const int mhi = (m >> 3), mlo = m & 7;
#pragma unroll
        for (int rp = 0; rp < 4; rp += 2) {
          const float p0 = __expf(fmaf(s[pi][fm][rp], SCALEc, zr[pi][fm][rp]));
          const float p1 = __expf(fmaf(s[pi][fm][rp + 1], SCALEc, zr[pi][fm][rp + 1]));
          unsigned int pk;
          asm("v_cvt_pk_bf16_f32 %0, %1, %2" : "=v"(pk) : "v"(p0), "v"(p1));
          const int n0 = wid * 32 + pi * 16 + lg * 4 + rp;
          ps[n0 * 64 + ((mhi ^ (n0 & 7)) << 3) + mlo] = (unsigned short)pk;
          const int n1 = n0 + 1;
          ps[n1 * 64 + ((mhi ^ (n1 & 7)) << 3) + mlo] = (unsigned short)(pk >> 16);
        }
      }
    // PV: acc[n][e] += P[n][m] * Vt[e][m]
    __builtin_amdgcn_s_setprio(1);
#pragma unroll
    for (int ksm = 0; ksm < 2; ++ksm) {
      const int k0 = ksm * 32 + lg * 8;
      const int kb8 = ksm * 4 + lg;
      const int na0 = wid * 32 + lr, na1 = wid * 32 + 16 + lr;
      bf16x8 pa0 = *(const bf16x8*)&ps[na0 * 64 + ((kb8 ^ (na0 & 7)) << 3)];
      bf16x8 pa1 = *(const bf16x8*)&ps[na1 * 64 + ((kb8 ^ (na1 & 7)) << 3)];
#pragma unroll
      for (int fe = 0; fe < 8; ++fe) {
        const int row = fe * 16 + lr;
        bf16x8 bv_ = *(const bf16x8*)&vt[cur][(row * 64 + k0) ^ ((row & 7) << 3)];
        acc[fe][0] = MFMA(pa0, bv_, acc[fe][0]);
        acc[fe][1] = MFMA(pa1, bv_, acc[fe][1]);
      }
    }
    __builtin_amdgcn_s_setprio(0);
    __syncthreads();  // reads of cur done; next-buf async loads drained
  }
  unsigned short* adst = Aw + ((size_t)(b * 512) + nt * 128) * 512 + h * 128;
#pragma unroll
  for (int pi = 0; pi < 2; ++pi)
#pragma unroll
    for (int r = 0; r < 4; ++r) {
      const int n = wid * 32 + pi * 16 + lg * 4 + r;
#pragma unroll
      for (int fe = 0; fe < 8; ++fe)
        adst[(size_t)n * 512 + fe * 16 + lr] = f2bf(acc[fe][pi][r]);
    }
}

// ---------------------------------------------------------------------------
// Fused MLP: h1 = relu(Acat@W1+b1) kept in LDS (as_ reused);
// out = LN(x + relu(h1@W2+b2))*gamma+beta. grid 256.
// ---------------------------------------------------------------------------
__global__ __launch_bounds__(256, 2) void k_mlp(
    const unsigned short* __restrict__ Aw, const unsigned short* __restrict__ Wt,
    const float* __restrict__ b1, const float* __restrict__ b2,
    const float* __restrict__ x, const float* __restrict__ gamma,
    const float* __restrict__ beta, float* __restrict__ out) {
  __shared__ unsigned short as_[128][136];
  __shared__ unsigned short w1[128][136];
  const int tid = threadIdx.x;
  const int wid = tid >> 6, lane = tid & 63, lr = lane & 15, lg = lane >> 4;
  const int r0 = blockIdx.x * 128;
  const unsigned short* w1t = Wt + 196608;
  const unsigned short* w2t = Wt + 262144;
  f32x4 acc[2][8];
#pragma unroll
  for (int i = 0; i < 2; ++i)
#pragma unroll
    for (int j = 0; j < 8; ++j) acc[i][j] = (f32x4)0.f;

  // ---- MLP1: Acat[128x512] @ W1t -> acc ----
  for (int ktile = 0; ktile < 4; ++ktile) {
#pragma unroll
    for (int i = 0; i < 8; ++i) {
      int f = tid + i * 256, row = f >> 4, c8 = (f & 15) * 8;
      *(uint4*)&as_[row][c8] =
          *(const uint4*)(Aw + (size_t)(r0 + row) * 512 + ktile * 128 + c8);
      *(uint4*)&w1[row][c8] =
          *(const uint4*)(w1t + (size_t)row * 512 + ktile * 128 + c8);
    }
    __syncthreads();
    __builtin_amdgcn_s_setprio(1);
#pragma unroll
    for (int ksi = 0; ksi < 4; ++ksi) {
      const int k0 = ksi * 32 + lg * 8;
      bf16x8 af0 = *(const bf16x8*)&as_[wid * 32 + lr][k0];
      bf16x8 af1 = *(const bf16x8*)&as_[wid * 32 + 16 + lr][k0];
#pragma unroll
      for (int fj = 0; fj < 8; ++fj) {
        bf16x8 bfr = *(const bf16x8*)&w1[fj * 16 + lr][k0];
        acc[0][fj] = MFMA(af0, bfr, acc[0][fj]);
        acc[1][fj] = MFMA(af1, bfr, acc[1][fj]);
      }
    }
    __builtin_amdgcn_s_setprio(0);
    __syncthreads();  // all reads of as_/w1 done
  }

  // ---- h1 = relu(acc + b1) -> bf16 into as_ (buffer dead after loop);
  //      w2 -> w1 buffer ----
  {
    float bb[8];
#pragma unroll
    for (int fj = 0; fj < 8; ++fj) bb[fj] = b1[fj * 16 + lr];
#pragma unroll
    for (int fi = 0; fi < 2; ++fi)
#pragma unroll
      for (int r = 0; r < 4; ++r) {
        const int row = wid * 32 + fi * 16 + lg * 4 + r;
#pragma unroll
        for (int fj = 0; fj < 8; ++fj)
          as_[row][fj * 16 + lr] = f2bf(fmaxf(acc[fi][fj][r] + bb[fj], 0.f));
      }
#pragma unroll
    for (int i = 0; i < 8; ++i) {
      int f = tid + i * 256, row = f >> 4, c8 = (f & 15) * 8;
      *(uint4*)&w1[row][c8] = *(const uint4*)(w2t + (size_t)row * 128 + c8);
    }
  }
  __syncthreads();  // h1 + w2 visible

  // ---- MLP2: h1[128x128] @ W2t -> out with residual + affine LN ----
#pragma unroll
  for (int i = 0; i < 2; ++i)
#pragma unroll
    for (int j = 0; j < 8; ++j) acc[i][j] = (f32x4)0.f;
  __builtin_amdgcn_s_setprio(1);
#pragma unroll
  for (int ksi = 0; ksi < 4; ++ksi) {
    const int k0 = ksi * 32 + lg * 8;
    bf16x8 af0 = *(const bf16x8*)&as_[wid * 32 + lr][k0];
    bf16x8 af1 = *(const bf16x8*)&as_[wid * 32 + 16 + lr][k0];
#pragma unroll
    for (int fj = 0; fj < 8; ++fj) {
      bf16x8 bfr = *(const bf16x8*)&w1[fj * 16 + lr][k0];
      acc[0][fj] = MFMA(af0, bfr, acc[0][fj]);
      acc[1][fj] = MFMA(af1, bfr, acc[1][fj]);
    }
  }
  __builtin_amdgcn_s_setprio(0);
  float bb[8], gm[8], bt[8];
#pragma unroll
  for (int fj = 0; fj < 8; ++fj) {
    bb[fj] = b2[fj * 16 + lr];
    gm[fj] = gamma[fj * 16 + lr];
    bt[fj] = beta[fj * 16 + lr];
  }
#pragma unroll
  for (int fi = 0; fi < 2; ++fi)
#pragma unroll
    for (int r = 0; r < 4; ++r) {
      const int gr = r0 + wid * 32 + fi * 16 + lg * 4 + r;
      float v[8], s = 0.f, s2 = 0.f;
#pragma unroll
      for (int fj = 0; fj < 8; ++fj) {
        v[fj] = fmaxf(acc[fi][fj][r] + bb[fj], 0.f) +
                x[(size_t)gr * 128 + fj * 16 + lr];
        s += v[fj]; s2 += v[fj] * v[fj];
      }
      s = red16(s); s2 = red16(s2);
      const float mu = s * (1.f / 128.f);
      const float inv = rsqrtf(s2 * (1.f / 128.f) - mu * mu + EPSc);
#pragma unroll
      for (int fj = 0; fj < 8; ++fj)
        out[(size_t)gr * 128 + fj * 16 + lr] =
            (v[fj] - mu) * inv * gm[fj] + bt[fj];
    }
}

extern "C" void kernel_launch(void* const* d_in, const int* in_sizes, int n_in,
                              void* d_out, int out_size, void* d_ws, size_t ws_size,
                              hipStream_t stream) {
  const float* x     = (const float*)d_in[0];
  const float* Wq    = (const float*)d_in[1];
  const float* bq    = (const float*)d_in[2];
  const float* Wk    = (const float*)d_in[3];
  const float* bk    = (const float*)d_in[4];
  const float* Wv    = (const float*)d_in[5];
  const float* bv    = (const float*)d_in[6];
  const float* W1    = (const float*)d_in[7];
  const float* b1    = (const float*)d_in[8];
  const float* W2    = (const float*)d_in[9];
  const float* b2    = (const float*)d_in[10];
  const float* gamma = (const float*)d_in[11];
  const float* beta  = (const float*)d_in[12];
  float* out = (float*)d_out;

  // ws layout (xb slot retained but unused): Qw 33.5MB | Kw 33.5MB |
  // Vtw 33.5MB | ZpA 33.5MB (Zp f32 -> Aw bf16) | Lz 4MB | Wts 0.6MB
  unsigned short* xb  = (unsigned short*)d_ws;
  unsigned short* Qw  = xb + 4194304;
  unsigned short* Kw  = Qw + 16777216;
  unsigned short* Vtw = Kw + 16777216;
  unsigned short* ZpA = Vtw + 16777216;
  float* Zp = (float*)ZpA;        // 8 x 1,048,576 f32 = 33.5MB (== Aw bytes)
  unsigned short* Aw = ZpA;       // alias: Zp dead after k_zred
  float* Lz = (float*)(ZpA + 16777216);
  unsigned short* Wts = (unsigned short*)(Lz + 1048576);

  k_conv <<<1088, 256, 0, stream>>>(Wq, Wk, Wv, W1, W2, Wts);
  k_proj <<<dim3(256, 12), 256, 0, stream>>>(x, Wts, bq, bk, bv, Qw, Kw, Vtw);
  k_z    <<<512, 256, 0, stream>>>(Qw, Kw, Zp);
  k_zred <<<1024, 256, 0, stream>>>(Zp, Lz);
  k_av   <<<1024, 256, 0, stream>>>(Qw, Kw, Vtw, Lz, Aw);
  k_mlp  <<<256, 256, 0, stream>>>(Aw, Wts, b1, b2, x, gamma, beta, out);
}

// Round 16
// 164.100 us; speedup vs baseline: 1.0730x; 1.0730x over previous
//
#include <hip/hip_runtime.h>
#include <hip/hip_bf16.h>

// ---------------------------------------------------------------------------
// Round 15 = R13 (passing, 168.1us) + ONLY the mlp1+mlp2 fusion from R14
// (correctness-proven there). R14's xb-elimination REVERTED: it doubled
// k_proj's staging traffic (12 x 8.4MB f32 re-reads) and regressed 8us.
//  - k_conv: fused x->bf16 + weight transpose converts (R13 form)
//  - k_proj: reads xb bf16 (R13 form)
//  - k_mlp: fused MLP1+MLP2, h1 kept in LDS (R14 form)
//  - k_z / k_zred / k_av byte-exact (FROZEN)
// ---------------------------------------------------------------------------

typedef __bf16 bf16x8 __attribute__((ext_vector_type(8)));
typedef float f32x4 __attribute__((ext_vector_type(4)));

constexpr float SCALEc = 1.0f / 11.0f;  // int(sqrt(128)) == 11 (faithful)
constexpr float EPSc = 1e-5f;

#define MFMA(a, b, c) __builtin_amdgcn_mfma_f32_16x16x32_bf16(a, b, c, 0, 0, 0)

static __device__ __forceinline__ unsigned short f2bf(float f) {
  unsigned int x = __float_as_uint(f);
  x += 0x7fffu + ((x >> 16) & 1u);  // RNE
  return (unsigned short)(x >> 16);
}
static __device__ __forceinline__ unsigned int pack2(float a, float b) {
  return (unsigned int)f2bf(a) | ((unsigned int)f2bf(b) << 16);
}
static __device__ __forceinline__ float red16(float v) {
  v += __shfl_xor(v, 1); v += __shfl_xor(v, 2);
  v += __shfl_xor(v, 4); v += __shfl_xor(v, 8);
  return v;
}
// async 16B global->LDS (LDS dest = wave-uniform base + lane*16, linear)
static __device__ __forceinline__ void gl_lds16(const void* g, void* l) {
  __builtin_amdgcn_global_load_lds(
      (const __attribute__((address_space(1))) void*)g,
      (__attribute__((address_space(3))) void*)l, 16, 0, 0);
}

// ---------------------------------------------------------------------------
// Fused converts: blocks [0,2048) -> xb = bf16(x); [2048,3136) -> Wt.
// ---------------------------------------------------------------------------
__global__ __launch_bounds__(256) void k_conv(
    const float* __restrict__ x, const float* __restrict__ Wq,
    const float* __restrict__ Wk, const float* __restrict__ Wv,
    const float* __restrict__ W1, const float* __restrict__ W2,
    unsigned short* __restrict__ xb, unsigned short* __restrict__ Wt) {
  const int bid = blockIdx.x;
  if (bid < 2048) {
    size_t i = ((size_t)bid * 256 + threadIdx.x) * 8;
    float4 a = *(const float4*)(x + i);
    float4 b = *(const float4*)(x + i + 4);
    uint4 o;
    o.x = pack2(a.x, a.y); o.y = pack2(a.z, a.w);
    o.z = pack2(b.x, b.y); o.w = pack2(b.z, b.w);
    *(uint4*)(xb + i) = o;
    return;
  }
  int t = (bid - 2048) * 256 + threadIdx.x;
  if (t < 196608) {
    int which = t >> 16, r = t & 65535;
    int h = r >> 14, idx = r & 16383;
    int d = idx >> 7, e = idx & 127;
    const float* W = which == 0 ? Wq : (which == 1 ? Wk : Wv);
    Wt[t] = f2bf(W[h * 16384 + e * 128 + d]);
  } else if (t < 262144) {
    int r = t - 196608, d = r >> 9, k = r & 511;
    Wt[t] = f2bf(W1[k * 128 + d]);
  } else if (t < 278528) {
    int r = t - 262144, d = r >> 7, k = r & 127;
    Wt[t] = f2bf(W2[k * 128 + d]);
  }
}

// ---------------------------------------------------------------------------
// Fused projections. grid (256, 12): y<8 -> Q/K proj+LN (proj=y>>2, h=y&3);
// y>=8 -> V proj transposed with cross-lane LN (h=y-8). (R13 form)
// ---------------------------------------------------------------------------
__global__ __launch_bounds__(256, 2) void k_proj(
    const unsigned short* __restrict__ xb, const unsigned short* __restrict__ Wt,
    const float* __restrict__ bq, const float* __restrict__ bk,
    const float* __restrict__ bv, unsigned short* __restrict__ Qw,
    unsigned short* __restrict__ Kw, unsigned short* __restrict__ Vtw) {
  __shared__ unsigned short xs[128][136];
  __shared__ unsigned short wt[128][136];
  const int tid = threadIdx.x;
  const int wid = tid >> 6, lane = tid & 63, lr = lane & 15, lg = lane >> 4;

  if (blockIdx.y < 8) {
    const int proj = blockIdx.y >> 2, h = blockIdx.y & 3;
    const int r0 = blockIdx.x * 128;
    const unsigned short* wsrc = Wt + proj * 65536 + h * 16384;
    const float* bias = (proj == 0 ? bq : bk) + h * 128;
    unsigned short* dst =
        (proj == 0 ? Qw : Kw) + ((size_t)((r0 >> 9) * 4 + h) * 512 + (r0 & 511)) * 128;

#pragma unroll
    for (int i = 0; i < 8; ++i) {
      int f = tid + i * 256, row = f >> 4, c8 = (f & 15) * 8;
      *(uint4*)&xs[row][c8] = *(const uint4*)(xb + (size_t)(r0 + row) * 128 + c8);
      *(uint4*)&wt[row][c8] = *(const uint4*)(wsrc + row * 128 + c8);
    }
    __syncthreads();

    const int wr0 = wid * 32;
    f32x4 acc[2][8];
#pragma unroll
    for (int i = 0; i < 2; ++i)
#pragma unroll
      for (int j = 0; j < 8; ++j) acc[i][j] = (f32x4)0.f;

    __builtin_amdgcn_s_setprio(1);
#pragma unroll
    for (int ksi = 0; ksi < 4; ++ksi) {
      const int k0 = ksi * 32 + lg * 8;
      bf16x8 af0 = *(const bf16x8*)&xs[wr0 + lr][k0];
      bf16x8 af1 = *(const bf16x8*)&xs[wr0 + 16 + lr][k0];
#pragma unroll
      for (int fj = 0; fj < 8; ++fj) {
        bf16x8 bfr = *(const bf16x8*)&wt[fj * 16 + lr][k0];
        acc[0][fj] = MFMA(af0, bfr, acc[0][fj]);
        acc[1][fj] = MFMA(af1, bfr, acc[1][fj]);
      }
    }
    __builtin_amdgcn_s_setprio(0);

    float bb[8];
#pragma unroll
    for (int fj = 0; fj < 8; ++fj) bb[fj] = bias[fj * 16 + lr];
#pragma unroll
    for (int fi = 0; fi < 2; ++fi)
#pragma unroll
      for (int r = 0; r < 4; ++r) {
        const int row = wr0 + fi * 16 + lg * 4 + r;
        float v[8], s = 0.f, s2 = 0.f;
#pragma unroll
        for (int fj = 0; fj < 8; ++fj) {
          v[fj] = acc[fi][fj][r] + bb[fj];
          s += v[fj]; s2 += v[fj] * v[fj];
        }
        s = red16(s); s2 = red16(s2);
        const float mu = s * (1.f / 128.f);
        const float inv = rsqrtf(s2 * (1.f / 128.f) - mu * mu + EPSc);
#pragma unroll
        for (int fj = 0; fj < 8; ++fj)
          dst[(size_t)row * 128 + fj * 16 + lr] = f2bf((v[fj] - mu) * inv);
      }
    return;
  }

  // ---- V projection transposed (h = blockIdx.y - 8) ----
  const int h = blockIdx.y - 8;
  const int n0 = blockIdx.x * 128;
  const unsigned short* wsrc = Wt + 131072 + h * 16384;
#pragma unroll
  for (int i = 0; i < 8; ++i) {
    int f = tid + i * 256, row = f >> 4, c8 = (f & 15) * 8;
    *(uint4*)&xs[row][c8] = *(const uint4*)(xb + (size_t)(n0 + row) * 128 + c8);
    *(uint4*)&wt[row][c8] = *(const uint4*)(wsrc + row * 128 + c8);
  }
  __syncthreads();
  const int wn0 = wid * 32;
  f32x4 acc[8][2];
#pragma unroll
  for (int i = 0; i < 8; ++i) {
    acc[i][0] = (f32x4)0.f; acc[i][1] = (f32x4)0.f;
  }
  __builtin_amdgcn_s_setprio(1);
#pragma unroll
  for (int ksi = 0; ksi < 4; ++ksi) {
    const int k0 = ksi * 32 + lg * 8;
    bf16x8 bf0 = *(const bf16x8*)&xs[wn0 + lr][k0];
    bf16x8 bf1 = *(const bf16x8*)&xs[wn0 + 16 + lr][k0];
#pragma unroll
    for (int fi = 0; fi < 8; ++fi) {
      bf16x8 af = *(const bf16x8*)&wt[fi * 16 + lr][k0];
      acc[fi][0] = MFMA(af, bf0, acc[fi][0]);
      acc[fi][1] = MFMA(af, bf1, acc[fi][1]);
    }
  }
  __builtin_amdgcn_s_setprio(0);
#pragma unroll
  for (int fi = 0; fi < 8; ++fi)
#pragma unroll
    for (int r = 0; r < 4; ++r) {
      const float bvv = bv[h * 128 + fi * 16 + lg * 4 + r];
      acc[fi][0][r] += bvv; acc[fi][1][r] += bvv;
    }
  const int gb = n0 >> 9;
  unsigned short* base = Vtw + (size_t)(gb * 4 + h) * 128 * 512;
#pragma unroll
  for (int fj = 0; fj < 2; ++fj) {
    float s = 0.f, s2 = 0.f;
#pragma unroll
    for (int fi = 0; fi < 8; ++fi)
#pragma unroll
      for (int r = 0; r < 4; ++r) {
        const float v = acc[fi][fj][r];
        s += v; s2 += v * v;
      }
    s += __shfl_xor(s, 16); s += __shfl_xor(s, 32);
    s2 += __shfl_xor(s2, 16); s2 += __shfl_xor(s2, 32);
    const float mu = s * (1.f / 128.f);
    const float inv = rsqrtf(s2 * (1.f / 128.f) - mu * mu + EPSc);
    const int nl = (n0 & 511) + wn0 + fj * 16 + lr;
#pragma unroll
    for (int fi = 0; fi < 8; ++fi)
#pragma unroll
      for (int r = 0; r < 4; ++r) {
        const int eout = fi * 16 + lg * 4 + r;
        base[(size_t)eout * 512 + nl] = f2bf((acc[fi][fj][r] - mu) * inv);
      }
  }
}

// ---------------------------------------------------------------------------
// Z partials: Zp[bs8,h,n,m] = sum_{8 b in group} exp(QK/11). grid 512 flat,
// XCD-swizzled (h fixed per class). Single-buffered 64KB LDS => 2 blocks/CU.
// Both-sides XOR swizzle + setprio. (FROZEN)
// ---------------------------------------------------------------------------
__global__ __launch_bounds__(256, 2) void k_z(
    const unsigned short* __restrict__ Qw, const unsigned short* __restrict__ Kw,
    float* __restrict__ Zp) {
  __shared__ __align__(16) unsigned short qs[128 * 128];
  __shared__ __align__(16) unsigned short ks_[128 * 128];
  const int tid = threadIdx.x;
  const int bid = blockIdx.x;
  const int c = bid & 7, s_ = bid >> 3;          // XCD class, sequence [0,64)
  const int combo = (s_ >> 4) * 8 + c;           // [0,32)
  const int h = combo & 3, bs8 = combo >> 2;     // h fixed per class
  const int t = s_ & 15;
  const int nt = t >> 2, mt = t & 3;
  const int wid = tid >> 6, lane = tid & 63, lr = lane & 15, lg = lane >> 4;
  const int srow = lane >> 4, ssub = lane & 15;  // staging role

  auto stageZ = [&](const unsigned short* qb, const unsigned short* kb) {
#pragma unroll
    for (int j = 0; j < 8; ++j) {
      const int cc = wid + 4 * j;                // 1KB chunk = 4 rows of 256B
      const int row = 4 * cc + srow;
      const int gof = row * 128 + ((ssub ^ (row & 7)) << 3);
      gl_lds16(qb + gof, &qs[cc * 512]);
      gl_lds16(kb + gof, &ks_[cc * 512]);
    }
  };

  f32x4 zacc[2][8];
#pragma unroll
  for (int i = 0; i < 2; ++i)
#pragma unroll
    for (int j = 0; j < 8; ++j) zacc[i][j] = (f32x4)0.f;

  const int b0 = bs8 * 8;
  for (int bi = 0; bi < 8; ++bi) {
    const int b = b0 + bi;
    stageZ(Qw + ((size_t)(b * 4 + h) * 512 + nt * 128) * 128,
           Kw + ((size_t)(b * 4 + h) * 512 + mt * 128) * 128);
    __syncthreads();  // vmcnt(0) drain: tiles ready
    f32x4 s[2][8];
#pragma unroll
    for (int i = 0; i < 2; ++i)
#pragma unroll
      for (int j = 0; j < 8; ++j) s[i][j] = (f32x4)0.f;
    __builtin_amdgcn_s_setprio(1);
#pragma unroll
    for (int ksi = 0; ksi < 4; ++ksi) {
      const int k0 = ksi * 32 + lg * 8;
      const int ra0 = wid * 32 + lr, ra1 = wid * 32 + 16 + lr;
      bf16x8 af0 = *(const bf16x8*)&qs[(ra0 * 128 + k0) ^ ((ra0 & 7) << 3)];
      bf16x8 af1 = *(const bf16x8*)&qs[(ra1 * 128 + k0) ^ ((ra1 & 7) << 3)];
#pragma unroll
      for (int fj = 0; fj < 8; ++fj) {
        const int rb = fj * 16 + lr;
        bf16x8 bfr = *(const bf16x8*)&ks_[(rb * 128 + k0) ^ ((rb & 7) << 3)];
        s[0][fj] = MFMA(af0, bfr, s[0][fj]);
        s[1][fj] = MFMA(af1, bfr, s[1][fj]);
      }
    }
    __builtin_amdgcn_s_setprio(0);
#pragma unroll
    for (int fi = 0; fi < 2; ++fi)
#pragma unroll
      for (int fj = 0; fj < 8; ++fj)
#pragma unroll
        for (int r = 0; r < 4; ++r)
          zacc[fi][fj][r] += __expf(s[fi][fj][r] * SCALEc);
    __syncthreads();  // all reads done -> next stage may overwrite
  }
#pragma unroll
  for (int fi = 0; fi < 2; ++fi)
#pragma unroll
    for (int r = 0; r < 4; ++r) {
      const int n = nt * 128 + wid * 32 + fi * 16 + lg * 4 + r;
      float* zp = Zp + (size_t)bs8 * 1048576 +
                  ((size_t)h * 512 + n) * 512 + mt * 128;
#pragma unroll
      for (int fj = 0; fj < 8; ++fj) zp[fj * 16 + lr] = zacc[fi][fj][r];
    }
}

// ---------------------------------------------------------------------------
// Lz = -ln(sum_{8 partials} Zp). grid 1024 x 256. (FROZEN)
// ---------------------------------------------------------------------------
__global__ __launch_bounds__(256) void k_zred(const float* __restrict__ Zp,
                                              float* __restrict__ Lz) {
  size_t i = ((size_t)blockIdx.x * 256 + threadIdx.x) * 4;
  float4 s = *(const float4*)(Zp + i);
#pragma unroll
  for (int p = 1; p < 8; ++p) {
    float4 t = *(const float4*)(Zp + (size_t)p * 1048576 + i);
    s.x += t.x; s.y += t.y; s.z += t.z; s.w += t.w;
  }
  float4 o = make_float4(-__logf(s.x), -__logf(s.y),
                         -__logf(s.z), -__logf(s.w));
  *(float4*)(Lz + i) = o;
}

// ---------------------------------------------------------------------------
// AV: A[b,h,n,e] = sum_m exp(QK/11 + Lz) * V -> Aw[b,n,h*128+e] bf16.
// grid 1024 flat, XCD-swizzled (h fixed per class). Q in registers;
// K/Vt async dbuf via global_load_lds + XOR; ps XOR-swizzled [128][64]
// => LDS 80KB => 2 blocks/CU. (FROZEN)
// ---------------------------------------------------------------------------
__global__ __launch_bounds__(256, 2) void k_av(
    const unsigned short* __restrict__ Qw, const unsigned short* __restrict__ Kw,
    const unsigned short* __restrict__ Vtw, const float* __restrict__ Lz,
    unsigned short* __restrict__ Aw) {
  __shared__ __align__(16) unsigned short kt[2][64 * 128];
  __shared__ __align__(16) unsigned short vt[2][128 * 64];
  __shared__ __align__(16) unsigned short ps[128 * 64];
  const int tid = threadIdx.x;
  const int bid = blockIdx.x;
  const int c = bid & 7, s_ = bid >> 3;
  const int g = s_ >> 2, nt = s_ & 3;
  const int bh = g * 8 + c;
  const int h = bh & 3, b = bh >> 2;
  const int wid = tid >> 6, lane = tid & 63, lr = lane & 15, lg = lane >> 4;

  const unsigned short* ksrc0 = Kw + (size_t)bh * 65536;
  const unsigned short* vsrc0 = Vtw + (size_t)bh * 65536;
  const unsigned short* qsrc = Qw + ((size_t)bh * 512 + nt * 128) * 128;

  auto stage = [&](int mt, int buf) {
    const unsigned short* kb = ksrc0 + (size_t)mt * 64 * 128;
#pragma unroll
    for (int j = 0; j < 4; ++j) {            // K tile: 64 rows x 256B
      const int cc = wid + 4 * j;
      const int row = 4 * cc + (lane >> 4), sub = lane & 15;
      gl_lds16(kb + row * 128 + ((sub ^ (row & 7)) << 3), &kt[buf][cc * 512]);
    }
    const unsigned short* vb = vsrc0 + mt * 64;
#pragma unroll
    for (int j = 0; j < 4; ++j) {            // Vt tile: 128 rows x 128B
      const int cc = wid + 4 * j;
      const int row = 8 * cc + (lane >> 3), sub = lane & 7;
      gl_lds16(vb + (size_t)row * 512 + ((sub ^ (row & 7)) << 3),
               &vt[buf][cc * 512]);
    }
  };

  stage(0, 0);
  // Q fragments -> registers (wave-private 32 rows)
  bf16x8 qreg[2][4];
#pragma unroll
  for (int pi = 0; pi < 2; ++pi)
#pragma unroll
    for (int ksi = 0; ksi < 4; ++ksi)
      qreg[pi][ksi] = *(const bf16x8*)(qsrc +
          (size_t)(wid * 32 + pi * 16 + lr) * 128 + ksi * 32 + lg * 8);
  __syncthreads();  // buf0 ready

  f32x4 acc[8][2];
#pragma unroll
  for (int i = 0; i < 8; ++i) { acc[i][0] = (f32x4)0.f; acc[i][1] = (f32x4)0.f; }
  const float* zbase = Lz + ((size_t)h * 512 + nt * 128) * 512;

  for (int mt = 0; mt < 8; ++mt) {
    const int cur = mt & 1;
    if (mt < 7) stage(mt + 1, cur ^ 1);
    // Lz for this tile (L2-resident per XCD class)
    float zr[2][4][4];
#pragma unroll
    for (int pi = 0; pi < 2; ++pi)
#pragma unroll
      for (int fm = 0; fm < 4; ++fm)
#pragma unroll
        for (int r = 0; r < 4; ++r)
          zr[pi][fm][r] = zbase[(size_t)(wid * 32 + pi * 16 + lg * 4 + r) * 512 +
                                mt * 64 + fm * 16 + lr];
    // S = Q K^T (32n x 64m per wave)
    f32x4 s[2][4];
#pragma unroll
    for (int i = 0; i < 2; ++i)
#pragma unroll
      for (int j = 0; j < 4; ++j) s[i][j] = (f32x4)0.f;
    __builtin_amdgcn_s_setprio(1);
#pragma unroll
    for (int ksi = 0; ksi < 4; ++ksi) {
      const int k0 = ksi * 32 + lg * 8;
#pragma unroll
      for (int fm = 0; fm < 4; ++fm) {
        const int row = fm * 16 + lr;
        bf16x8 bfr = *(const bf16x8*)&kt[cur][(row * 128 + k0) ^ ((row & 7) << 3)];
        s[0][fm] = MFMA(qreg[0][ksi], bfr, s[0][fm]);
        s[1][fm] = MFMA(qreg[1][ksi], bfr, s[1][fm]);
      }
    }
    __builtin_amdgcn_s_setprio(0);
    // P = exp(s/11 + lz) -> bf16 via cvt_pk -> ps (wave-private rows).
    // ps XOR layout: idx(n,m) = n*64 + (((m>>3)^(n&7))<<3) + (m&7).
#pragma unroll
    for (int pi = 0; pi < 2; ++pi)
#pragma unroll
      for (int fm = 0; fm < 4; ++fm) {
        const int m = fm * 16 + lr;
        const int mhi = (m >> 3), mlo = m & 7;
#pragma unroll
        for (int rp = 0; rp < 4; rp += 2) {
          const float p0 = __expf(fmaf(s[pi][fm][rp], SCALEc, zr[pi][fm][rp]));
          const float p1 = __expf(fmaf(s[pi][fm][rp + 1], SCALEc, zr[pi][fm][rp + 1]));
          unsigned int pk;
          asm("v_cvt_pk_bf16_f32 %0, %1, %2" : "=v"(pk) : "v"(p0), "v"(p1));
          const int n0 = wid * 32 + pi * 16 + lg * 4 + rp;
          ps[n0 * 64 + ((mhi ^ (n0 & 7)) << 3) + mlo] = (unsigned short)pk;
          const int n1 = n0 + 1;
          ps[n1 * 64 + ((mhi ^ (n1 & 7)) << 3) + mlo] = (unsigned short)(pk >> 16);
        }
      }
    // PV: acc[n][e] += P[n][m] * Vt[e][m]
    __builtin_amdgcn_s_setprio(1);
#pragma unroll
    for (int ksm = 0; ksm < 2; ++ksm) {
      const int k0 = ksm * 32 + lg * 8;
      const int kb8 = ksm * 4 + lg;
      const int na0 = wid * 32 + lr, na1 = wid * 32 + 16 + lr;
      bf16x8 pa0 = *(const bf16x8*)&ps[na0 * 64 + ((kb8 ^ (na0 & 7)) << 3)];
      bf16x8 pa1 = *(const bf16x8*)&ps[na1 * 64 + ((kb8 ^ (na1 & 7)) << 3)];
#pragma unroll
      for (int fe = 0; fe < 8; ++fe) {
        const int row = fe * 16 + lr;
        bf16x8 bv_ = *(const bf16x8*)&vt[cur][(row * 64 + k0) ^ ((row & 7) << 3)];
        acc[fe][0] = MFMA(pa0, bv_, acc[fe][0]);
        acc[fe][1] = MFMA(pa1, bv_, acc[fe][1]);
      }
    }
    __builtin_amdgcn_s_setprio(0);
    __syncthreads();  // reads of cur done; next-buf async loads drained
  }
  unsigned short* adst = Aw + ((size_t)(b * 512) + nt * 128) * 512 + h * 128;
#pragma unroll
  for (int pi = 0; pi < 2; ++pi)
#pragma unroll
    for (int r = 0; r < 4; ++r) {
      const int n = wid * 32 + pi * 16 + lg * 4 + r;
#pragma unroll
      for (int fe = 0; fe < 8; ++fe)
        adst[(size_t)n * 512 + fe * 16 + lr] = f2bf(acc[fe][pi][r]);
    }
}

// ---------------------------------------------------------------------------
// Fused MLP: h1 = relu(Acat@W1+b1) kept in LDS (as_ reused);
// out = LN(x + relu(h1@W2+b2))*gamma+beta. grid 256. (R14 form, proven)
// ---------------------------------------------------------------------------
__global__ __launch_bounds__(256, 2) void k_mlp(
    const unsigned short* __restrict__ Aw, const unsigned short* __restrict__ Wt,
    const float* __restrict__ b1, const float* __restrict__ b2,
    const float* __restrict__ x, const float* __restrict__ gamma,
    const float* __restrict__ beta, float* __restrict__ out) {
  __shared__ unsigned short as_[128][136];
  __shared__ unsigned short w1[128][136];
  const int tid = threadIdx.x;
  const int wid = tid >> 6, lane = tid & 63, lr = lane & 15, lg = lane >> 4;
  const int r0 = blockIdx.x * 128;
  const unsigned short* w1t = Wt + 196608;
  const unsigned short* w2t = Wt + 262144;
  f32x4 acc[2][8];
#pragma unroll
  for (int i = 0; i < 2; ++i)
#pragma unroll
    for (int j = 0; j < 8; ++j) acc[i][j] = (f32x4)0.f;

  // ---- MLP1: Acat[128x512] @ W1t -> acc ----
  for (int ktile = 0; ktile < 4; ++ktile) {
#pragma unroll
    for (int i = 0; i < 8; ++i) {
      int f = tid + i * 256, row = f >> 4, c8 = (f & 15) * 8;
      *(uint4*)&as_[row][c8] =
          *(const uint4*)(Aw + (size_t)(r0 + row) * 512 + ktile * 128 + c8);
      *(uint4*)&w1[row][c8] =
          *(const uint4*)(w1t + (size_t)row * 512 + ktile * 128 + c8);
    }
    __syncthreads();
    __builtin_amdgcn_s_setprio(1);
#pragma unroll
    for (int ksi = 0; ksi < 4; ++ksi) {
      const int k0 = ksi * 32 + lg * 8;
      bf16x8 af0 = *(const bf16x8*)&as_[wid * 32 + lr][k0];
      bf16x8 af1 = *(const bf16x8*)&as_[wid * 32 + 16 + lr][k0];
#pragma unroll
      for (int fj = 0; fj < 8; ++fj) {
        bf16x8 bfr = *(const bf16x8*)&w1[fj * 16 + lr][k0];
        acc[0][fj] = MFMA(af0, bfr, acc[0][fj]);
        acc[1][fj] = MFMA(af1, bfr, acc[1][fj]);
      }
    }
    __builtin_amdgcn_s_setprio(0);
    __syncthreads();  // all reads of as_/w1 done
  }

  // ---- h1 = relu(acc + b1) -> bf16 into as_ ; w2 -> w1 buffer ----
  {
    float bb[8];
#pragma unroll
    for (int fj = 0; fj < 8; ++fj) bb[fj] = b1[fj * 16 + lr];
#pragma unroll
    for (int fi = 0; fi < 2; ++fi)
#pragma unroll
      for (int r = 0; r < 4; ++r) {
        const int row = wid * 32 + fi * 16 + lg * 4 + r;
#pragma unroll
        for (int fj = 0; fj < 8; ++fj)
          as_[row][fj * 16 + lr] = f2bf(fmaxf(acc[fi][fj][r] + bb[fj], 0.f));
      }
#pragma unroll
    for (int i = 0; i < 8; ++i) {
      int f = tid + i * 256, row = f >> 4, c8 = (f & 15) * 8;
      *(uint4*)&w1[row][c8] = *(const uint4*)(w2t + (size_t)row * 128 + c8);
    }
  }
  __syncthreads();  // h1 + w2 visible

  // ---- MLP2: h1[128x128] @ W2t -> out with residual + affine LN ----
#pragma unroll
  for (int i = 0; i < 2; ++i)
#pragma unroll
    for (int j = 0; j < 8; ++j) acc[i][j] = (f32x4)0.f;
  __builtin_amdgcn_s_setprio(1);
#pragma unroll
  for (int ksi = 0; ksi < 4; ++ksi) {
    const int k0 = ksi * 32 + lg * 8;
    bf16x8 af0 = *(const bf16x8*)&as_[wid * 32 + lr][k0];
    bf16x8 af1 = *(const bf16x8*)&as_[wid * 32 + 16 + lr][k0];
#pragma unroll
    for (int fj = 0; fj < 8; ++fj) {
      bf16x8 bfr = *(const bf16x8*)&w1[fj * 16 + lr][k0];
      acc[0][fj] = MFMA(af0, bfr, acc[0][fj]);
      acc[1][fj] = MFMA(af1, bfr, acc[1][fj]);
    }
  }
  __builtin_amdgcn_s_setprio(0);
  float bb[8], gm[8], bt[8];
#pragma unroll
  for (int fj = 0; fj < 8; ++fj) {
    bb[fj] = b2[fj * 16 + lr];
    gm[fj] = gamma[fj * 16 + lr];
    bt[fj] = beta[fj * 16 + lr];
  }
#pragma unroll
  for (int fi = 0; fi < 2; ++fi)
#pragma unroll
    for (int r = 0; r < 4; ++r) {
      const int gr = r0 + wid * 32 + fi * 16 + lg * 4 + r;
      float v[8], s = 0.f, s2 = 0.f;
#pragma unroll
      for (int fj = 0; fj < 8; ++fj) {
        v[fj] = fmaxf(acc[fi][fj][r] + bb[fj], 0.f) +
                x[(size_t)gr * 128 + fj * 16 + lr];
        s += v[fj]; s2 += v[fj] * v[fj];
      }
      s = red16(s); s2 = red16(s2);
      const float mu = s * (1.f / 128.f);
      const float inv = rsqrtf(s2 * (1.f / 128.f) - mu * mu + EPSc);
#pragma unroll
      for (int fj = 0; fj < 8; ++fj)
        out[(size_t)gr * 128 + fj * 16 + lr] =
            (v[fj] - mu) * inv * gm[fj] + bt[fj];
    }
}

extern "C" void kernel_launch(void* const* d_in, const int* in_sizes, int n_in,
                              void* d_out, int out_size, void* d_ws, size_t ws_size,
                              hipStream_t stream) {
  const float* x     = (const float*)d_in[0];
  const float* Wq    = (const float*)d_in[1];
  const float* bq    = (const float*)d_in[2];
  const float* Wk    = (const float*)d_in[3];
  const float* bk    = (const float*)d_in[4];
  const float* Wv    = (const float*)d_in[5];
  const float* bv    = (const float*)d_in[6];
  const float* W1    = (const float*)d_in[7];
  const float* b1    = (const float*)d_in[8];
  const float* W2    = (const float*)d_in[9];
  const float* b2    = (const float*)d_in[10];
  const float* gamma = (const float*)d_in[11];
  const float* beta  = (const float*)d_in[12];
  float* out = (float*)d_out;

  // ws layout: xb 8MB | Qw 33.5MB | Kw 33.5MB | Vtw 33.5MB |
  // ZpA 33.5MB (Zp f32 -> Aw bf16) | Lz 4MB | Wts 0.6MB
  unsigned short* xb  = (unsigned short*)d_ws;
  unsigned short* Qw  = xb + 4194304;
  unsigned short* Kw  = Qw + 16777216;
  unsigned short* Vtw = Kw + 16777216;
  unsigned short* ZpA = Vtw + 16777216;
  float* Zp = (float*)ZpA;        // 8 x 1,048,576 f32 = 33.5MB (== Aw bytes)
  unsigned short* Aw = ZpA;       // alias: Zp dead after k_zred
  float* Lz = (float*)(ZpA + 16777216);
  unsigned short* Wts = (unsigned short*)(Lz + 1048576);

  k_conv <<<3136, 256, 0, stream>>>(x, Wq, Wk, Wv, W1, W2, xb, Wts);
  k_proj <<<dim3(256, 12), 256, 0, stream>>>(xb, Wts, bq, bk, bv, Qw, Kw, Vtw);
  k_z    <<<512, 256, 0, stream>>>(Qw, Kw, Zp);
  k_zred <<<1024, 256, 0, stream>>>(Zp, Lz);
  k_av   <<<1024, 256, 0, stream>>>(Qw, Kw, Vtw, Lz, Aw);
  k_mlp  <<<256, 256, 0, stream>>>(Aw, Wts, b1, b2, x, gamma, beta, out);
}

// Round 17
// 163.798 us; speedup vs baseline: 1.0750x; 1.0018x over previous
//
#include <hip/hip_runtime.h>
#include <hip/hip_bf16.h>

// ---------------------------------------------------------------------------
// Round 16 = R15 (passing, 164.1us) + Q/K projection slice fusion:
// k_proj grid (256,12) -> (256,8). y<4: fused Q+K for h=y -- stage xs ONCE,
// MFMA(Q), barrier, reload wt<-Wk (Q epilogue overlaps), barrier, MFMA(K).
// Same buffer-reuse pattern as the proven k_mlp fusion. y>=4: V transposed
// (unchanged). k_conv / k_z / k_zred / k_av / k_mlp byte-exact R15 (FROZEN).
// ---------------------------------------------------------------------------

typedef __bf16 bf16x8 __attribute__((ext_vector_type(8)));
typedef float f32x4 __attribute__((ext_vector_type(4)));

constexpr float SCALEc = 1.0f / 11.0f;  // int(sqrt(128)) == 11 (faithful)
constexpr float EPSc = 1e-5f;

#define MFMA(a, b, c) __builtin_amdgcn_mfma_f32_16x16x32_bf16(a, b, c, 0, 0, 0)

static __device__ __forceinline__ unsigned short f2bf(float f) {
  unsigned int x = __float_as_uint(f);
  x += 0x7fffu + ((x >> 16) & 1u);  // RNE
  return (unsigned short)(x >> 16);
}
static __device__ __forceinline__ unsigned int pack2(float a, float b) {
  return (unsigned int)f2bf(a) | ((unsigned int)f2bf(b) << 16);
}
static __device__ __forceinline__ float red16(float v) {
  v += __shfl_xor(v, 1); v += __shfl_xor(v, 2);
  v += __shfl_xor(v, 4); v += __shfl_xor(v, 8);
  return v;
}
// async 16B global->LDS (LDS dest = wave-uniform base + lane*16, linear)
static __device__ __forceinline__ void gl_lds16(const void* g, void* l) {
  __builtin_amdgcn_global_load_lds(
      (const __attribute__((address_space(1))) void*)g,
      (__attribute__((address_space(3))) void*)l, 16, 0, 0);
}

// ---------------------------------------------------------------------------
// Fused converts: blocks [0,2048) -> xb = bf16(x); [2048,3136) -> Wt.
// ---------------------------------------------------------------------------
__global__ __launch_bounds__(256) void k_conv(
    const float* __restrict__ x, const float* __restrict__ Wq,
    const float* __restrict__ Wk, const float* __restrict__ Wv,
    const float* __restrict__ W1, const float* __restrict__ W2,
    unsigned short* __restrict__ xb, unsigned short* __restrict__ Wt) {
  const int bid = blockIdx.x;
  if (bid < 2048) {
    size_t i = ((size_t)bid * 256 + threadIdx.x) * 8;
    float4 a = *(const float4*)(x + i);
    float4 b = *(const float4*)(x + i + 4);
    uint4 o;
    o.x = pack2(a.x, a.y); o.y = pack2(a.z, a.w);
    o.z = pack2(b.x, b.y); o.w = pack2(b.z, b.w);
    *(uint4*)(xb + i) = o;
    return;
  }
  int t = (bid - 2048) * 256 + threadIdx.x;
  if (t < 196608) {
    int which = t >> 16, r = t & 65535;
    int h = r >> 14, idx = r & 16383;
    int d = idx >> 7, e = idx & 127;
    const float* W = which == 0 ? Wq : (which == 1 ? Wk : Wv);
    Wt[t] = f2bf(W[h * 16384 + e * 128 + d]);
  } else if (t < 262144) {
    int r = t - 196608, d = r >> 9, k = r & 511;
    Wt[t] = f2bf(W1[k * 128 + d]);
  } else if (t < 278528) {
    int r = t - 262144, d = r >> 7, k = r & 127;
    Wt[t] = f2bf(W2[k * 128 + d]);
  }
}

// ---------------------------------------------------------------------------
// Fused projections. grid (256, 8):
//  y<4: Q+K for h=y (xs staged once; wt reloaded between Q and K phases)
//  y>=4: V proj transposed with cross-lane LN (h=y-4)
// ---------------------------------------------------------------------------
__global__ __launch_bounds__(256, 2) void k_proj(
    const unsigned short* __restrict__ xb, const unsigned short* __restrict__ Wt,
    const float* __restrict__ bq, const float* __restrict__ bk,
    const float* __restrict__ bv, unsigned short* __restrict__ Qw,
    unsigned short* __restrict__ Kw, unsigned short* __restrict__ Vtw) {
  __shared__ unsigned short xs[128][136];
  __shared__ unsigned short wt[128][136];
  const int tid = threadIdx.x;
  const int wid = tid >> 6, lane = tid & 63, lr = lane & 15, lg = lane >> 4;

  if (blockIdx.y < 4) {
    const int h = blockIdx.y;
    const int r0 = blockIdx.x * 128;
    const unsigned short* wsrcQ = Wt + h * 16384;            // proj 0
    const unsigned short* wsrcK = Wt + 65536 + h * 16384;    // proj 1
    const size_t drow = ((size_t)((r0 >> 9) * 4 + h) * 512 + (r0 & 511)) * 128;
    unsigned short* dstQ = Qw + drow;
    unsigned short* dstK = Kw + drow;
    const int wr0 = wid * 32;

    // stage xs (once) + Wq
#pragma unroll
    for (int i = 0; i < 8; ++i) {
      int f = tid + i * 256, row = f >> 4, c8 = (f & 15) * 8;
      *(uint4*)&xs[row][c8] = *(const uint4*)(xb + (size_t)(r0 + row) * 128 + c8);
      *(uint4*)&wt[row][c8] = *(const uint4*)(wsrcQ + row * 128 + c8);
    }
    __syncthreads();

    // ---- Q phase ----
    f32x4 acc[2][8];
#pragma unroll
    for (int i = 0; i < 2; ++i)
#pragma unroll
      for (int j = 0; j < 8; ++j) acc[i][j] = (f32x4)0.f;
    __builtin_amdgcn_s_setprio(1);
#pragma unroll
    for (int ksi = 0; ksi < 4; ++ksi) {
      const int k0 = ksi * 32 + lg * 8;
      bf16x8 af0 = *(const bf16x8*)&xs[wr0 + lr][k0];
      bf16x8 af1 = *(const bf16x8*)&xs[wr0 + 16 + lr][k0];
#pragma unroll
      for (int fj = 0; fj < 8; ++fj) {
        bf16x8 bfr = *(const bf16x8*)&wt[fj * 16 + lr][k0];
        acc[0][fj] = MFMA(af0, bfr, acc[0][fj]);
        acc[1][fj] = MFMA(af1, bfr, acc[1][fj]);
      }
    }
    __builtin_amdgcn_s_setprio(0);
    __syncthreads();  // all wt reads done -> safe to overwrite with Wk

    // issue Wk loads; Q epilogue overlaps them
#pragma unroll
    for (int i = 0; i < 8; ++i) {
      int f = tid + i * 256, row = f >> 4, c8 = (f & 15) * 8;
      *(uint4*)&wt[row][c8] = *(const uint4*)(wsrcK + row * 128 + c8);
    }
    {
      float bb[8];
#pragma unroll
      for (int fj = 0; fj < 8; ++fj) bb[fj] = bq[h * 128 + fj * 16 + lr];
#pragma unroll
      for (int fi = 0; fi < 2; ++fi)
#pragma unroll
        for (int r = 0; r < 4; ++r) {
          const int row = wr0 + fi * 16 + lg * 4 + r;
          float v[8], s = 0.f, s2 = 0.f;
#pragma unroll
          for (int fj = 0; fj < 8; ++fj) {
            v[fj] = acc[fi][fj][r] + bb[fj];
            s += v[fj]; s2 += v[fj] * v[fj];
          }
          s = red16(s); s2 = red16(s2);
          const float mu = s * (1.f / 128.f);
          const float inv = rsqrtf(s2 * (1.f / 128.f) - mu * mu + EPSc);
#pragma unroll
          for (int fj = 0; fj < 8; ++fj)
            dstQ[(size_t)row * 128 + fj * 16 + lr] = f2bf((v[fj] - mu) * inv);
        }
    }
    __syncthreads();  // Wk visible

    // ---- K phase ----
#pragma unroll
    for (int i = 0; i < 2; ++i)
#pragma unroll
      for (int j = 0; j < 8; ++j) acc[i][j] = (f32x4)0.f;
    __builtin_amdgcn_s_setprio(1);
#pragma unroll
    for (int ksi = 0; ksi < 4; ++ksi) {
      const int k0 = ksi * 32 + lg * 8;
      bf16x8 af0 = *(const bf16x8*)&xs[wr0 + lr][k0];
      bf16x8 af1 = *(const bf16x8*)&xs[wr0 + 16 + lr][k0];
#pragma unroll
      for (int fj = 0; fj < 8; ++fj) {
        bf16x8 bfr = *(const bf16x8*)&wt[fj * 16 + lr][k0];
        acc[0][fj] = MFMA(af0, bfr, acc[0][fj]);
        acc[1][fj] = MFMA(af1, bfr, acc[1][fj]);
      }
    }
    __builtin_amdgcn_s_setprio(0);
    {
      float bb[8];
#pragma unroll
      for (int fj = 0; fj < 8; ++fj) bb[fj] = bk[h * 128 + fj * 16 + lr];
#pragma unroll
      for (int fi = 0; fi < 2; ++fi)
#pragma unroll
        for (int r = 0; r < 4; ++r) {
          const int row = wr0 + fi * 16 + lg * 4 + r;
          float v[8], s = 0.f, s2 = 0.f;
#pragma unroll
          for (int fj = 0; fj < 8; ++fj) {
            v[fj] = acc[fi][fj][r] + bb[fj];
            s += v[fj]; s2 += v[fj] * v[fj];
          }
          s = red16(s); s2 = red16(s2);
          const float mu = s * (1.f / 128.f);
          const float inv = rsqrtf(s2 * (1.f / 128.f) - mu * mu + EPSc);
#pragma unroll
          for (int fj = 0; fj < 8; ++fj)
            dstK[(size_t)row * 128 + fj * 16 + lr] = f2bf((v[fj] - mu) * inv);
        }
    }
    return;
  }

  // ---- V projection transposed (h = blockIdx.y - 4) ----
  const int h = blockIdx.y - 4;
  const int n0 = blockIdx.x * 128;
  const unsigned short* wsrc = Wt + 131072 + h * 16384;
#pragma unroll
  for (int i = 0; i < 8; ++i) {
    int f = tid + i * 256, row = f >> 4, c8 = (f & 15) * 8;
    *(uint4*)&xs[row][c8] = *(const uint4*)(xb + (size_t)(n0 + row) * 128 + c8);
    *(uint4*)&wt[row][c8] = *(const uint4*)(wsrc + row * 128 + c8);
  }
  __syncthreads();
  const int wn0 = wid * 32;
  f32x4 acc[8][2];
#pragma unroll
  for (int i = 0; i < 8; ++i) {
    acc[i][0] = (f32x4)0.f; acc[i][1] = (f32x4)0.f;
  }
  __builtin_amdgcn_s_setprio(1);
#pragma unroll
  for (int ksi = 0; ksi < 4; ++ksi) {
    const int k0 = ksi * 32 + lg * 8;
    bf16x8 bf0 = *(const bf16x8*)&xs[wn0 + lr][k0];
    bf16x8 bf1 = *(const bf16x8*)&xs[wn0 + 16 + lr][k0];
#pragma unroll
    for (int fi = 0; fi < 8; ++fi) {
      bf16x8 af = *(const bf16x8*)&wt[fi * 16 + lr][k0];
      acc[fi][0] = MFMA(af, bf0, acc[fi][0]);
      acc[fi][1] = MFMA(af, bf1, acc[fi][1]);
    }
  }
  __builtin_amdgcn_s_setprio(0);
#pragma unroll
  for (int fi = 0; fi < 8; ++fi)
#pragma unroll
    for (int r = 0; r < 4; ++r) {
      const float bvv = bv[h * 128 + fi * 16 + lg * 4 + r];
      acc[fi][0][r] += bvv; acc[fi][1][r] += bvv;
    }
  const int gb = n0 >> 9;
  unsigned short* base = Vtw + (size_t)(gb * 4 + h) * 128 * 512;
#pragma unroll
  for (int fj = 0; fj < 2; ++fj) {
    float s = 0.f, s2 = 0.f;
#pragma unroll
    for (int fi = 0; fi < 8; ++fi)
#pragma unroll
      for (int r = 0; r < 4; ++r) {
        const float v = acc[fi][fj][r];
        s += v; s2 += v * v;
      }
    s += __shfl_xor(s, 16); s += __shfl_xor(s, 32);
    s2 += __shfl_xor(s2, 16); s2 += __shfl_xor(s2, 32);
    const float mu = s * (1.f / 128.f);
    const float inv = rsqrtf(s2 * (1.f / 128.f) - mu * mu + EPSc);
    const int nl = (n0 & 511) + wn0 + fj * 16 + lr;
#pragma unroll
    for (int fi = 0; fi < 8; ++fi)
#pragma unroll
      for (int r = 0; r < 4; ++r) {
        const int eout = fi * 16 + lg * 4 + r;
        base[(size_t)eout * 512 + nl] = f2bf((acc[fi][fj][r] - mu) * inv);
      }
  }
}

// ---------------------------------------------------------------------------
// Z partials: Zp[bs8,h,n,m] = sum_{8 b in group} exp(QK/11). grid 512 flat,
// XCD-swizzled (h fixed per class). Single-buffered 64KB LDS => 2 blocks/CU.
// Both-sides XOR swizzle + setprio. (FROZEN)
// ---------------------------------------------------------------------------
__global__ __launch_bounds__(256, 2) void k_z(
    const unsigned short* __restrict__ Qw, const unsigned short* __restrict__ Kw,
    float* __restrict__ Zp) {
  __shared__ __align__(16) unsigned short qs[128 * 128];
  __shared__ __align__(16) unsigned short ks_[128 * 128];
  const int tid = threadIdx.x;
  const int bid = blockIdx.x;
  const int c = bid & 7, s_ = bid >> 3;          // XCD class, sequence [0,64)
  const int combo = (s_ >> 4) * 8 + c;           // [0,32)
  const int h = combo & 3, bs8 = combo >> 2;     // h fixed per class
  const int t = s_ & 15;
  const int nt = t >> 2, mt = t & 3;
  const int wid = tid >> 6, lane = tid & 63, lr = lane & 15, lg = lane >> 4;
  const int srow = lane >> 4, ssub = lane & 15;  // staging role

  auto stageZ = [&](const unsigned short* qb, const unsigned short* kb) {
#pragma unroll
    for (int j = 0; j < 8; ++j) {
      const int cc = wid + 4 * j;                // 1KB chunk = 4 rows of 256B
      const int row = 4 * cc + srow;
      const int gof = row * 128 + ((ssub ^ (row & 7)) << 3);
      gl_lds16(qb + gof, &qs[cc * 512]);
      gl_lds16(kb + gof, &ks_[cc * 512]);
    }
  };

  f32x4 zacc[2][8];
#pragma unroll
  for (int i = 0; i < 2; ++i)
#pragma unroll
    for (int j = 0; j < 8; ++j) zacc[i][j] = (f32x4)0.f;

  const int b0 = bs8 * 8;
  for (int bi = 0; bi < 8; ++bi) {
    const int b = b0 + bi;
    stageZ(Qw + ((size_t)(b * 4 + h) * 512 + nt * 128) * 128,
           Kw + ((size_t)(b * 4 + h) * 512 + mt * 128) * 128);
    __syncthreads();  // vmcnt(0) drain: tiles ready
    f32x4 s[2][8];
#pragma unroll
    for (int i = 0; i < 2; ++i)
#pragma unroll
      for (int j = 0; j < 8; ++j) s[i][j] = (f32x4)0.f;
    __builtin_amdgcn_s_setprio(1);
#pragma unroll
    for (int ksi = 0; ksi < 4; ++ksi) {
      const int k0 = ksi * 32 + lg * 8;
      const int ra0 = wid * 32 + lr, ra1 = wid * 32 + 16 + lr;
      bf16x8 af0 = *(const bf16x8*)&qs[(ra0 * 128 + k0) ^ ((ra0 & 7) << 3)];
      bf16x8 af1 = *(const bf16x8*)&qs[(ra1 * 128 + k0) ^ ((ra1 & 7) << 3)];
#pragma unroll
      for (int fj = 0; fj < 8; ++fj) {
        const int rb = fj * 16 + lr;
        bf16x8 bfr = *(const bf16x8*)&ks_[(rb * 128 + k0) ^ ((rb & 7) << 3)];
        s[0][fj] = MFMA(af0, bfr, s[0][fj]);
        s[1][fj] = MFMA(af1, bfr, s[1][fj]);
      }
    }
    __builtin_amdgcn_s_setprio(0);
#pragma unroll
    for (int fi = 0; fi < 2; ++fi)
#pragma unroll
      for (int fj = 0; fj < 8; ++fj)
#pragma unroll
        for (int r = 0; r < 4; ++r)
          zacc[fi][fj][r] += __expf(s[fi][fj][r] * SCALEc);
    __syncthreads();  // all reads done -> next stage may overwrite
  }
#pragma unroll
  for (int fi = 0; fi < 2; ++fi)
#pragma unroll
    for (int r = 0; r < 4; ++r) {
      const int n = nt * 128 + wid * 32 + fi * 16 + lg * 4 + r;
      float* zp = Zp + (size_t)bs8 * 1048576 +
                  ((size_t)h * 512 + n) * 512 + mt * 128;
#pragma unroll
      for (int fj = 0; fj < 8; ++fj) zp[fj * 16 + lr] = zacc[fi][fj][r];
    }
}

// ---------------------------------------------------------------------------
// Lz = -ln(sum_{8 partials} Zp). grid 1024 x 256. (FROZEN)
// ---------------------------------------------------------------------------
__global__ __launch_bounds__(256) void k_zred(const float* __restrict__ Zp,
                                              float* __restrict__ Lz) {
  size_t i = ((size_t)blockIdx.x * 256 + threadIdx.x) * 4;
  float4 s = *(const float4*)(Zp + i);
#pragma unroll
  for (int p = 1; p < 8; ++p) {
    float4 t = *(const float4*)(Zp + (size_t)p * 1048576 + i);
    s.x += t.x; s.y += t.y; s.z += t.z; s.w += t.w;
  }
  float4 o = make_float4(-__logf(s.x), -__logf(s.y),
                         -__logf(s.z), -__logf(s.w));
  *(float4*)(Lz + i) = o;
}

// ---------------------------------------------------------------------------
// AV: A[b,h,n,e] = sum_m exp(QK/11 + Lz) * V -> Aw[b,n,h*128+e] bf16.
// grid 1024 flat, XCD-swizzled (h fixed per class). Q in registers;
// K/Vt async dbuf via global_load_lds + XOR; ps XOR-swizzled [128][64]
// => LDS 80KB => 2 blocks/CU. (FROZEN)
// ---------------------------------------------------------------------------
__global__ __launch_bounds__(256, 2) void k_av(
    const unsigned short* __restrict__ Qw, const unsigned short* __restrict__ Kw,
    const unsigned short* __restrict__ Vtw, const float* __restrict__ Lz,
    unsigned short* __restrict__ Aw) {
  __shared__ __align__(16) unsigned short kt[2][64 * 128];
  __shared__ __align__(16) unsigned short vt[2][128 * 64];
  __shared__ __align__(16) unsigned short ps[128 * 64];
  const int tid = threadIdx.x;
  const int bid = blockIdx.x;
  const int c = bid & 7, s_ = bid >> 3;
  const int g = s_ >> 2, nt = s_ & 3;
  const int bh = g * 8 + c;
  const int h = bh & 3, b = bh >> 2;
  const int wid = tid >> 6, lane = tid & 63, lr = lane & 15, lg = lane >> 4;

  const unsigned short* ksrc0 = Kw + (size_t)bh * 65536;
  const unsigned short* vsrc0 = Vtw + (size_t)bh * 65536;
  const unsigned short* qsrc = Qw + ((size_t)bh * 512 + nt * 128) * 128;

  auto stage = [&](int mt, int buf) {
    const unsigned short* kb = ksrc0 + (size_t)mt * 64 * 128;
#pragma unroll
    for (int j = 0; j < 4; ++j) {            // K tile: 64 rows x 256B
      const int cc = wid + 4 * j;
      const int row = 4 * cc + (lane >> 4), sub = lane & 15;
      gl_lds16(kb + row * 128 + ((sub ^ (row & 7)) << 3), &kt[buf][cc * 512]);
    }
    const unsigned short* vb = vsrc0 + mt * 64;
#pragma unroll
    for (int j = 0; j < 4; ++j) {            // Vt tile: 128 rows x 128B
      const int cc = wid + 4 * j;
      const int row = 8 * cc + (lane >> 3), sub = lane & 7;
      gl_lds16(vb + (size_t)row * 512 + ((sub ^ (row & 7)) << 3),
               &vt[buf][cc * 512]);
    }
  };

  stage(0, 0);
  // Q fragments -> registers (wave-private 32 rows)
  bf16x8 qreg[2][4];
#pragma unroll
  for (int pi = 0; pi < 2; ++pi)
#pragma unroll
    for (int ksi = 0; ksi < 4; ++ksi)
      qreg[pi][ksi] = *(const bf16x8*)(qsrc +
          (size_t)(wid * 32 + pi * 16 + lr) * 128 + ksi * 32 + lg * 8);
  __syncthreads();  // buf0 ready

  f32x4 acc[8][2];
#pragma unroll
  for (int i = 0; i < 8; ++i) { acc[i][0] = (f32x4)0.f; acc[i][1] = (f32x4)0.f; }
  const float* zbase = Lz + ((size_t)h * 512 + nt * 128) * 512;

  for (int mt = 0; mt < 8; ++mt) {
    const int cur = mt & 1;
    if (mt < 7) stage(mt + 1, cur ^ 1);
    // Lz for this tile (L2-resident per XCD class)
    float zr[2][4][4];
#pragma unroll
    for (int pi = 0; pi < 2; ++pi)
#pragma unroll
      for (int fm = 0; fm < 4; ++fm)
#pragma unroll
        for (int r = 0; r < 4; ++r)
          zr[pi][fm][r] = zbase[(size_t)(wid * 32 + pi * 16 + lg * 4 + r) * 512 +
                                mt * 64 + fm * 16 + lr];
    // S = Q K^T (32n x 64m per wave)
    f32x4 s[2][4];
#pragma unroll
    for (int i = 0; i < 2; ++i)
#pragma unroll
      for (int j = 0; j < 4; ++j) s[i][j] = (f32x4)0.f;
    __builtin_amdgcn_s_setprio(1);
#pragma unroll
    for (int ksi = 0; ksi < 4; ++ksi) {
      const int k0 = ksi * 32 + lg * 8;
#pragma unroll
      for (int fm = 0; fm < 4; ++fm) {
        const int row = fm * 16 + lr;
        bf16x8 bfr = *(const bf16x8*)&kt[cur][(row * 128 + k0) ^ ((row & 7) << 3)];
        s[0][fm] = MFMA(qreg[0][ksi], bfr, s[0][fm]);
        s[1][fm] = MFMA(qreg[1][ksi], bfr, s[1][fm]);
      }
    }
    __builtin_amdgcn_s_setprio(0);
    // P = exp(s/11 + lz) -> bf16 via cvt_pk -> ps (wave-private rows).
    // ps XOR layout: idx(n,m) = n*64 + (((m>>3)^(n&7))<<3) + (m&7).
#pragma unroll
    for (int pi = 0; pi < 2; ++pi)
#pragma unroll
      for (int fm = 0; fm < 4; ++fm) {
        const int m = fm * 16 + lr;
        const int mhi = (m >> 3), mlo = m & 7;
#pragma unroll
        for (int rp = 0; rp < 4; rp += 2) {
          const float p0 = __expf(fmaf(s[pi][fm][rp], SCALEc, zr[pi][fm][rp]));
          const float p1 = __expf(fmaf(s[pi][fm][rp + 1], SCALEc, zr[pi][fm][rp + 1]));
          unsigned int pk;
          asm("v_cvt_pk_bf16_f32 %0, %1, %2" : "=v"(pk) : "v"(p0), "v"(p1));
          const int n0 = wid * 32 + pi * 16 + lg * 4 + rp;
          ps[n0 * 64 + ((mhi ^ (n0 & 7)) << 3) + mlo] = (unsigned short)pk;
          const int n1 = n0 + 1;
          ps[n1 * 64 + ((mhi ^ (n1 & 7)) << 3) + mlo] = (unsigned short)(pk >> 16);
        }
      }
    // PV: acc[n][e] += P[n][m] * Vt[e][m]
    __builtin_amdgcn_s_setprio(1);
#pragma unroll
    for (int ksm = 0; ksm < 2; ++ksm) {
      const int k0 = ksm * 32 + lg * 8;
      const int kb8 = ksm * 4 + lg;
      const int na0 = wid * 32 + lr, na1 = wid * 32 + 16 + lr;
      bf16x8 pa0 = *(const bf16x8*)&ps[na0 * 64 + ((kb8 ^ (na0 & 7)) << 3)];
      bf16x8 pa1 = *(const bf16x8*)&ps[na1 * 64 + ((kb8 ^ (na1 & 7)) << 3)];
#pragma unroll
      for (int fe = 0; fe < 8; ++fe) {
        const int row = fe * 16 + lr;
        bf16x8 bv_ = *(const bf16x8*)&vt[cur][(row * 64 + k0) ^ ((row & 7) << 3)];
        acc[fe][0] = MFMA(pa0, bv_, acc[fe][0]);
        acc[fe][1] = MFMA(pa1, bv_, acc[fe][1]);
      }
    }
    __builtin_amdgcn_s_setprio(0);
    __syncthreads();  // reads of cur done; next-buf async loads drained
  }
  unsigned short* adst = Aw + ((size_t)(b * 512) + nt * 128) * 512 + h * 128;
#pragma unroll
  for (int pi = 0; pi < 2; ++pi)
#pragma unroll
    for (int r = 0; r < 4; ++r) {
      const int n = wid * 32 + pi * 16 + lg * 4 + r;
#pragma unroll
      for (int fe = 0; fe < 8; ++fe)
        adst[(size_t)n * 512 + fe * 16 + lr] = f2bf(acc[fe][pi][r]);
    }
}

// ---------------------------------------------------------------------------
// Fused MLP: h1 = relu(Acat@W1+b1) kept in LDS (as_ reused);
// out = LN(x + relu(h1@W2+b2))*gamma+beta. grid 256. (FROZEN, R14/R15)
// ---------------------------------------------------------------------------
__global__ __launch_bounds__(256, 2) void k_mlp(
    const unsigned short* __restrict__ Aw, const unsigned short* __restrict__ Wt,
    const float* __restrict__ b1, const float* __restrict__ b2,
    const float* __restrict__ x, const float* __restrict__ gamma,
    const float* __restrict__ beta, float* __restrict__ out) {
  __shared__ unsigned short as_[128][136];
  __shared__ unsigned short w1[128][136];
  const int tid = threadIdx.x;
  const int wid = tid >> 6, lane = tid & 63, lr = lane & 15, lg = lane >> 4;
  const int r0 = blockIdx.x * 128;
  const unsigned short* w1t = Wt + 196608;
  const unsigned short* w2t = Wt + 262144;
  f32x4 acc[2][8];
#pragma unroll
  for (int i = 0; i < 2; ++i)
#pragma unroll
    for (int j = 0; j < 8; ++j) acc[i][j] = (f32x4)0.f;

  // ---- MLP1: Acat[128x512] @ W1t -> acc ----
  for (int ktile = 0; ktile < 4; ++ktile) {
#pragma unroll
    for (int i = 0; i < 8; ++i) {
      int f = tid + i * 256, row = f >> 4, c8 = (f & 15) * 8;
      *(uint4*)&as_[row][c8] =
          *(const uint4*)(Aw + (size_t)(r0 + row) * 512 + ktile * 128 + c8);
      *(uint4*)&w1[row][c8] =
          *(const uint4*)(w1t + (size_t)row * 512 + ktile * 128 + c8);
    }
    __syncthreads();
    __builtin_amdgcn_s_setprio(1);
#pragma unroll
    for (int ksi = 0; ksi < 4; ++ksi) {
      const int k0 = ksi * 32 + lg * 8;
      bf16x8 af0 = *(const bf16x8*)&as_[wid * 32 + lr][k0];
      bf16x8 af1 = *(const bf16x8*)&as_[wid * 32 + 16 + lr][k0];
#pragma unroll
      for (int fj = 0; fj < 8; ++fj) {
        bf16x8 bfr = *(const bf16x8*)&w1[fj * 16 + lr][k0];
        acc[0][fj] = MFMA(af0, bfr, acc[0][fj]);
        acc[1][fj] = MFMA(af1, bfr, acc[1][fj]);
      }
    }
    __builtin_amdgcn_s_setprio(0);
    __syncthreads();  // all reads of as_/w1 done
  }

  // ---- h1 = relu(acc + b1) -> bf16 into as_ ; w2 -> w1 buffer ----
  {
    float bb[8];
#pragma unroll
    for (int fj = 0; fj < 8; ++fj) bb[fj] = b1[fj * 16 + lr];
#pragma unroll
    for (int fi = 0; fi < 2; ++fi)
#pragma unroll
      for (int r = 0; r < 4; ++r) {
        const int row = wid * 32 + fi * 16 + lg * 4 + r;
#pragma unroll
        for (int fj = 0; fj < 8; ++fj)
          as_[row][fj * 16 + lr] = f2bf(fmaxf(acc[fi][fj][r] + bb[fj], 0.f));
      }
#pragma unroll
    for (int i = 0; i < 8; ++i) {
      int f = tid + i * 256, row = f >> 4, c8 = (f & 15) * 8;
      *(uint4*)&w1[row][c8] = *(const uint4*)(w2t + (size_t)row * 128 + c8);
    }
  }
  __syncthreads();  // h1 + w2 visible

  // ---- MLP2: h1[128x128] @ W2t -> out with residual + affine LN ----
#pragma unroll
  for (int i = 0; i < 2; ++i)
#pragma unroll
    for (int j = 0; j < 8; ++j) acc[i][j] = (f32x4)0.f;
  __builtin_amdgcn_s_setprio(1);
#pragma unroll
  for (int ksi = 0; ksi < 4; ++ksi) {
    const int k0 = ksi * 32 + lg * 8;
    bf16x8 af0 = *(const bf16x8*)&as_[wid * 32 + lr][k0];
    bf16x8 af1 = *(const bf16x8*)&as_[wid * 32 + 16 + lr][k0];
#pragma unroll
    for (int fj = 0; fj < 8; ++fj) {
      bf16x8 bfr = *(const bf16x8*)&w1[fj * 16 + lr][k0];
      acc[0][fj] = MFMA(af0, bfr, acc[0][fj]);
      acc[1][fj] = MFMA(af1, bfr, acc[1][fj]);
    }
  }
  __builtin_amdgcn_s_setprio(0);
  float bb[8], gm[8], bt[8];
#pragma unroll
  for (int fj = 0; fj < 8; ++fj) {
    bb[fj] = b2[fj * 16 + lr];
    gm[fj] = gamma[fj * 16 + lr];
    bt[fj] = beta[fj * 16 + lr];
  }
#pragma unroll
  for (int fi = 0; fi < 2; ++fi)
#pragma unroll
    for (int r = 0; r < 4; ++r) {
      const int gr = r0 + wid * 32 + fi * 16 + lg * 4 + r;
      float v[8], s = 0.f, s2 = 0.f;
#pragma unroll
      for (int fj = 0; fj < 8; ++fj) {
        v[fj] = fmaxf(acc[fi][fj][r] + bb[fj], 0.f) +
                x[(size_t)gr * 128 + fj * 16 + lr];
        s += v[fj]; s2 += v[fj] * v[fj];
      }
      s = red16(s); s2 = red16(s2);
      const float mu = s * (1.f / 128.f);
      const float inv = rsqrtf(s2 * (1.f / 128.f) - mu * mu + EPSc);
#pragma unroll
      for (int fj = 0; fj < 8; ++fj)
        out[(size_t)gr * 128 + fj * 16 + lr] =
            (v[fj] - mu) * inv * gm[fj] + bt[fj];
    }
}

extern "C" void kernel_launch(void* const* d_in, const int* in_sizes, int n_in,
                              void* d_out, int out_size, void* d_ws, size_t ws_size,
                              hipStream_t stream) {
  const float* x     = (const float*)d_in[0];
  const float* Wq    = (const float*)d_in[1];
  const float* bq    = (const float*)d_in[2];
  const float* Wk    = (const float*)d_in[3];
  const float* bk    = (const float*)d_in[4];
  const float* Wv    = (const float*)d_in[5];
  const float* bv    = (const float*)d_in[6];
  const float* W1    = (const float*)d_in[7];
  const float* b1    = (const float*)d_in[8];
  const float* W2    = (const float*)d_in[9];
  const float* b2    = (const float*)d_in[10];
  const float* gamma = (const float*)d_in[11];
  const float* beta  = (const float*)d_in[12];
  float* out = (float*)d_out;

  // ws layout: xb 8MB | Qw 33.5MB | Kw 33.5MB | Vtw 33.5MB |
  // ZpA 33.5MB (Zp f32 -> Aw bf16) | Lz 4MB | Wts 0.6MB
  unsigned short* xb  = (unsigned short*)d_ws;
  unsigned short* Qw  = xb + 4194304;
  unsigned short* Kw  = Qw + 16777216;
  unsigned short* Vtw = Kw + 16777216;
  unsigned short* ZpA = Vtw + 16777216;
  float* Zp = (float*)ZpA;        // 8 x 1,048,576 f32 = 33.5MB (== Aw bytes)
  unsigned short* Aw = ZpA;       // alias: Zp dead after k_zred
  float* Lz = (float*)(ZpA + 16777216);
  unsigned short* Wts = (unsigned short*)(Lz + 1048576);

  k_conv <<<3136, 256, 0, stream>>>(x, Wq, Wk, Wv, W1, W2, xb, Wts);
  k_proj <<<dim3(256, 8), 256, 0, stream>>>(xb, Wts, bq, bk, bv, Qw, Kw, Vtw);
  k_z    <<<512, 256, 0, stream>>>(Qw, Kw, Zp);
  k_zred <<<1024, 256, 0, stream>>>(Zp, Lz);
  k_av   <<<1024, 256, 0, stream>>>(Qw, Kw, Vtw, Lz, Aw);
  k_mlp  <<<256, 256, 0, stream>>>(Aw, Wts, b1, b2, x, gamma, beta, out);
}

// Round 18
// 161.105 us; speedup vs baseline: 1.0930x; 1.0167x over previous
//
#include <hip/hip_runtime.h>
#include <hip/hip_bf16.h>

// ---------------------------------------------------------------------------
// Round 17 = R16 (passing, 163.8us) + Z-partial traffic halved:
//  - k_z stores partials as bf16 (accumulation still f32; only store rounds)
//  - k_zred reads ushort8 partials, sums in f32, writes Lz f32 (unchanged
//    format for frozen k_av). Grid 1024 -> 512.
// Only the k_z EPILOGUE store type changed -- staging/MFMA/swizzle structure
// untouched. k_conv/k_proj/k_av/k_mlp byte-exact R16 (FROZEN).
// ---------------------------------------------------------------------------

typedef __bf16 bf16x8 __attribute__((ext_vector_type(8)));
typedef unsigned short u16x8 __attribute__((ext_vector_type(8)));
typedef float f32x4 __attribute__((ext_vector_type(4)));

constexpr float SCALEc = 1.0f / 11.0f;  // int(sqrt(128)) == 11 (faithful)
constexpr float EPSc = 1e-5f;

#define MFMA(a, b, c) __builtin_amdgcn_mfma_f32_16x16x32_bf16(a, b, c, 0, 0, 0)

static __device__ __forceinline__ unsigned short f2bf(float f) {
  unsigned int x = __float_as_uint(f);
  x += 0x7fffu + ((x >> 16) & 1u);  // RNE
  return (unsigned short)(x >> 16);
}
static __device__ __forceinline__ float bf2f(unsigned short u) {
  return __uint_as_float(((unsigned int)u) << 16);
}
static __device__ __forceinline__ unsigned int pack2(float a, float b) {
  return (unsigned int)f2bf(a) | ((unsigned int)f2bf(b) << 16);
}
static __device__ __forceinline__ float red16(float v) {
  v += __shfl_xor(v, 1); v += __shfl_xor(v, 2);
  v += __shfl_xor(v, 4); v += __shfl_xor(v, 8);
  return v;
}
// async 16B global->LDS (LDS dest = wave-uniform base + lane*16, linear)
static __device__ __forceinline__ void gl_lds16(const void* g, void* l) {
  __builtin_amdgcn_global_load_lds(
      (const __attribute__((address_space(1))) void*)g,
      (__attribute__((address_space(3))) void*)l, 16, 0, 0);
}

// ---------------------------------------------------------------------------
// Fused converts: blocks [0,2048) -> xb = bf16(x); [2048,3136) -> Wt.
// ---------------------------------------------------------------------------
__global__ __launch_bounds__(256) void k_conv(
    const float* __restrict__ x, const float* __restrict__ Wq,
    const float* __restrict__ Wk, const float* __restrict__ Wv,
    const float* __restrict__ W1, const float* __restrict__ W2,
    unsigned short* __restrict__ xb, unsigned short* __restrict__ Wt) {
  const int bid = blockIdx.x;
  if (bid < 2048) {
    size_t i = ((size_t)bid * 256 + threadIdx.x) * 8;
    float4 a = *(const float4*)(x + i);
    float4 b = *(const float4*)(x + i + 4);
    uint4 o;
    o.x = pack2(a.x, a.y); o.y = pack2(a.z, a.w);
    o.z = pack2(b.x, b.y); o.w = pack2(b.z, b.w);
    *(uint4*)(xb + i) = o;
    return;
  }
  int t = (bid - 2048) * 256 + threadIdx.x;
  if (t < 196608) {
    int which = t >> 16, r = t & 65535;
    int h = r >> 14, idx = r & 16383;
    int d = idx >> 7, e = idx & 127;
    const float* W = which == 0 ? Wq : (which == 1 ? Wk : Wv);
    Wt[t] = f2bf(W[h * 16384 + e * 128 + d]);
  } else if (t < 262144) {
    int r = t - 196608, d = r >> 9, k = r & 511;
    Wt[t] = f2bf(W1[k * 128 + d]);
  } else if (t < 278528) {
    int r = t - 262144, d = r >> 7, k = r & 127;
    Wt[t] = f2bf(W2[k * 128 + d]);
  }
}

// ---------------------------------------------------------------------------
// Fused projections. grid (256, 8):
//  y<4: Q+K for h=y (xs staged once; wt reloaded between Q and K phases)
//  y>=4: V proj transposed with cross-lane LN (h=y-4). (R16 form, FROZEN)
// ---------------------------------------------------------------------------
__global__ __launch_bounds__(256, 2) void k_proj(
    const unsigned short* __restrict__ xb, const unsigned short* __restrict__ Wt,
    const float* __restrict__ bq, const float* __restrict__ bk,
    const float* __restrict__ bv, unsigned short* __restrict__ Qw,
    unsigned short* __restrict__ Kw, unsigned short* __restrict__ Vtw) {
  __shared__ unsigned short xs[128][136];
  __shared__ unsigned short wt[128][136];
  const int tid = threadIdx.x;
  const int wid = tid >> 6, lane = tid & 63, lr = lane & 15, lg = lane >> 4;

  if (blockIdx.y < 4) {
    const int h = blockIdx.y;
    const int r0 = blockIdx.x * 128;
    const unsigned short* wsrcQ = Wt + h * 16384;            // proj 0
    const unsigned short* wsrcK = Wt + 65536 + h * 16384;    // proj 1
    const size_t drow = ((size_t)((r0 >> 9) * 4 + h) * 512 + (r0 & 511)) * 128;
    unsigned short* dstQ = Qw + drow;
    unsigned short* dstK = Kw + drow;
    const int wr0 = wid * 32;

    // stage xs (once) + Wq
#pragma unroll
    for (int i = 0; i < 8; ++i) {
      int f = tid + i * 256, row = f >> 4, c8 = (f & 15) * 8;
      *(uint4*)&xs[row][c8] = *(const uint4*)(xb + (size_t)(r0 + row) * 128 + c8);
      *(uint4*)&wt[row][c8] = *(const uint4*)(wsrcQ + row * 128 + c8);
    }
    __syncthreads();

    // ---- Q phase ----
    f32x4 acc[2][8];
#pragma unroll
    for (int i = 0; i < 2; ++i)
#pragma unroll
      for (int j = 0; j < 8; ++j) acc[i][j] = (f32x4)0.f;
    __builtin_amdgcn_s_setprio(1);
#pragma unroll
    for (int ksi = 0; ksi < 4; ++ksi) {
      const int k0 = ksi * 32 + lg * 8;
      bf16x8 af0 = *(const bf16x8*)&xs[wr0 + lr][k0];
      bf16x8 af1 = *(const bf16x8*)&xs[wr0 + 16 + lr][k0];
#pragma unroll
      for (int fj = 0; fj < 8; ++fj) {
        bf16x8 bfr = *(const bf16x8*)&wt[fj * 16 + lr][k0];
        acc[0][fj] = MFMA(af0, bfr, acc[0][fj]);
        acc[1][fj] = MFMA(af1, bfr, acc[1][fj]);
      }
    }
    __builtin_amdgcn_s_setprio(0);
    __syncthreads();  // all wt reads done -> safe to overwrite with Wk

    // issue Wk loads; Q epilogue overlaps them
#pragma unroll
    for (int i = 0; i < 8; ++i) {
      int f = tid + i * 256, row = f >> 4, c8 = (f & 15) * 8;
      *(uint4*)&wt[row][c8] = *(const uint4*)(wsrcK + row * 128 + c8);
    }
    {
      float bb[8];
#pragma unroll
      for (int fj = 0; fj < 8; ++fj) bb[fj] = bq[h * 128 + fj * 16 + lr];
#pragma unroll
      for (int fi = 0; fi < 2; ++fi)
#pragma unroll
        for (int r = 0; r < 4; ++r) {
          const int row = wr0 + fi * 16 + lg * 4 + r;
          float v[8], s = 0.f, s2 = 0.f;
#pragma unroll
          for (int fj = 0; fj < 8; ++fj) {
            v[fj] = acc[fi][fj][r] + bb[fj];
            s += v[fj]; s2 += v[fj] * v[fj];
          }
          s = red16(s); s2 = red16(s2);
          const float mu = s * (1.f / 128.f);
          const float inv = rsqrtf(s2 * (1.f / 128.f) - mu * mu + EPSc);
#pragma unroll
          for (int fj = 0; fj < 8; ++fj)
            dstQ[(size_t)row * 128 + fj * 16 + lr] = f2bf((v[fj] - mu) * inv);
        }
    }
    __syncthreads();  // Wk visible

    // ---- K phase ----
#pragma unroll
    for (int i = 0; i < 2; ++i)
#pragma unroll
      for (int j = 0; j < 8; ++j) acc[i][j] = (f32x4)0.f;
    __builtin_amdgcn_s_setprio(1);
#pragma unroll
    for (int ksi = 0; ksi < 4; ++ksi) {
      const int k0 = ksi * 32 + lg * 8;
      bf16x8 af0 = *(const bf16x8*)&xs[wr0 + lr][k0];
      bf16x8 af1 = *(const bf16x8*)&xs[wr0 + 16 + lr][k0];
#pragma unroll
      for (int fj = 0; fj < 8; ++fj) {
        bf16x8 bfr = *(const bf16x8*)&wt[fj * 16 + lr][k0];
        acc[0][fj] = MFMA(af0, bfr, acc[0][fj]);
        acc[1][fj] = MFMA(af1, bfr, acc[1][fj]);
      }
    }
    __builtin_amdgcn_s_setprio(0);
    {
      float bb[8];
#pragma unroll
      for (int fj = 0; fj < 8; ++fj) bb[fj] = bk[h * 128 + fj * 16 + lr];
#pragma unroll
      for (int fi = 0; fi < 2; ++fi)
#pragma unroll
        for (int r = 0; r < 4; ++r) {
          const int row = wr0 + fi * 16 + lg * 4 + r;
          float v[8], s = 0.f, s2 = 0.f;
#pragma unroll
          for (int fj = 0; fj < 8; ++fj) {
            v[fj] = acc[fi][fj][r] + bb[fj];
            s += v[fj]; s2 += v[fj] * v[fj];
          }
          s = red16(s); s2 = red16(s2);
          const float mu = s * (1.f / 128.f);
          const float inv = rsqrtf(s2 * (1.f / 128.f) - mu * mu + EPSc);
#pragma unroll
          for (int fj = 0; fj < 8; ++fj)
            dstK[(size_t)row * 128 + fj * 16 + lr] = f2bf((v[fj] - mu) * inv);
        }
    }
    return;
  }

  // ---- V projection transposed (h = blockIdx.y - 4) ----
  const int h = blockIdx.y - 4;
  const int n0 = blockIdx.x * 128;
  const unsigned short* wsrc = Wt + 131072 + h * 16384;
#pragma unroll
  for (int i = 0; i < 8; ++i) {
    int f = tid + i * 256, row = f >> 4, c8 = (f & 15) * 8;
    *(uint4*)&xs[row][c8] = *(const uint4*)(xb + (size_t)(n0 + row) * 128 + c8);
    *(uint4*)&wt[row][c8] = *(const uint4*)(wsrc + row * 128 + c8);
  }
  __syncthreads();
  const int wn0 = wid * 32;
  f32x4 acc[8][2];
#pragma unroll
  for (int i = 0; i < 8; ++i) {
    acc[i][0] = (f32x4)0.f; acc[i][1] = (f32x4)0.f;
  }
  __builtin_amdgcn_s_setprio(1);
#pragma unroll
  for (int ksi = 0; ksi < 4; ++ksi) {
    const int k0 = ksi * 32 + lg * 8;
    bf16x8 bf0 = *(const bf16x8*)&xs[wn0 + lr][k0];
    bf16x8 bf1 = *(const bf16x8*)&xs[wn0 + 16 + lr][k0];
#pragma unroll
    for (int fi = 0; fi < 8; ++fi) {
      bf16x8 af = *(const bf16x8*)&wt[fi * 16 + lr][k0];
      acc[fi][0] = MFMA(af, bf0, acc[fi][0]);
      acc[fi][1] = MFMA(af, bf1, acc[fi][1]);
    }
  }
  __builtin_amdgcn_s_setprio(0);
#pragma unroll
  for (int fi = 0; fi < 8; ++fi)
#pragma unroll
    for (int r = 0; r < 4; ++r) {
      const float bvv = bv[h * 128 + fi * 16 + lg * 4 + r];
      acc[fi][0][r] += bvv; acc[fi][1][r] += bvv;
    }
  const int gb = n0 >> 9;
  unsigned short* base = Vtw + (size_t)(gb * 4 + h) * 128 * 512;
#pragma unroll
  for (int fj = 0; fj < 2; ++fj) {
    float s = 0.f, s2 = 0.f;
#pragma unroll
    for (int fi = 0; fi < 8; ++fi)
#pragma unroll
      for (int r = 0; r < 4; ++r) {
        const float v = acc[fi][fj][r];
        s += v; s2 += v * v;
      }
    s += __shfl_xor(s, 16); s += __shfl_xor(s, 32);
    s2 += __shfl_xor(s2, 16); s2 += __shfl_xor(s2, 32);
    const float mu = s * (1.f / 128.f);
    const float inv = rsqrtf(s2 * (1.f / 128.f) - mu * mu + EPSc);
    const int nl = (n0 & 511) + wn0 + fj * 16 + lr;
#pragma unroll
    for (int fi = 0; fi < 8; ++fi)
#pragma unroll
      for (int r = 0; r < 4; ++r) {
        const int eout = fi * 16 + lg * 4 + r;
        base[(size_t)eout * 512 + nl] = f2bf((acc[fi][fj][r] - mu) * inv);
      }
  }
}

// ---------------------------------------------------------------------------
// Z partials: Zpb[bs8,h,n,m] = bf16(sum_{8 b} exp(QK/11)). grid 512 flat,
// XCD-swizzled. Accumulation f32; ONLY the partial store rounds to bf16.
// Staging/MFMA/swizzle structure identical to R16 (FROZEN core).
// ---------------------------------------------------------------------------
__global__ __launch_bounds__(256, 2) void k_z(
    const unsigned short* __restrict__ Qw, const unsigned short* __restrict__ Kw,
    unsigned short* __restrict__ Zpb) {
  __shared__ __align__(16) unsigned short qs[128 * 128];
  __shared__ __align__(16) unsigned short ks_[128 * 128];
  const int tid = threadIdx.x;
  const int bid = blockIdx.x;
  const int c = bid & 7, s_ = bid >> 3;          // XCD class, sequence [0,64)
  const int combo = (s_ >> 4) * 8 + c;           // [0,32)
  const int h = combo & 3, bs8 = combo >> 2;     // h fixed per class
  const int t = s_ & 15;
  const int nt = t >> 2, mt = t & 3;
  const int wid = tid >> 6, lane = tid & 63, lr = lane & 15, lg = lane >> 4;
  const int srow = lane >> 4, ssub = lane & 15;  // staging role

  auto stageZ = [&](const unsigned short* qb, const unsigned short* kb) {
#pragma unroll
    for (int j = 0; j < 8; ++j) {
      const int cc = wid + 4 * j;                // 1KB chunk = 4 rows of 256B
      const int row = 4 * cc + srow;
      const int gof = row * 128 + ((ssub ^ (row & 7)) << 3);
      gl_lds16(qb + gof, &qs[cc * 512]);
      gl_lds16(kb + gof, &ks_[cc * 512]);
    }
  };

  f32x4 zacc[2][8];
#pragma unroll
  for (int i = 0; i < 2; ++i)
#pragma unroll
    for (int j = 0; j < 8; ++j) zacc[i][j] = (f32x4)0.f;

  const int b0 = bs8 * 8;
  for (int bi = 0; bi < 8; ++bi) {
    const int b = b0 + bi;
    stageZ(Qw + ((size_t)(b * 4 + h) * 512 + nt * 128) * 128,
           Kw + ((size_t)(b * 4 + h) * 512 + mt * 128) * 128);
    __syncthreads();  // vmcnt(0) drain: tiles ready
    f32x4 s[2][8];
#pragma unroll
    for (int i = 0; i < 2; ++i)
#pragma unroll
      for (int j = 0; j < 8; ++j) s[i][j] = (f32x4)0.f;
    __builtin_amdgcn_s_setprio(1);
#pragma unroll
    for (int ksi = 0; ksi < 4; ++ksi) {
      const int k0 = ksi * 32 + lg * 8;
      const int ra0 = wid * 32 + lr, ra1 = wid * 32 + 16 + lr;
      bf16x8 af0 = *(const bf16x8*)&qs[(ra0 * 128 + k0) ^ ((ra0 & 7) << 3)];
      bf16x8 af1 = *(const bf16x8*)&qs[(ra1 * 128 + k0) ^ ((ra1 & 7) << 3)];
#pragma unroll
      for (int fj = 0; fj < 8; ++fj) {
        const int rb = fj * 16 + lr;
        bf16x8 bfr = *(const bf16x8*)&ks_[(rb * 128 + k0) ^ ((rb & 7) << 3)];
        s[0][fj] = MFMA(af0, bfr, s[0][fj]);
        s[1][fj] = MFMA(af1, bfr, s[1][fj]);
      }
    }
    __builtin_amdgcn_s_setprio(0);
#pragma unroll
    for (int fi = 0; fi < 2; ++fi)
#pragma unroll
      for (int fj = 0; fj < 8; ++fj)
#pragma unroll
        for (int r = 0; r < 4; ++r)
          zacc[fi][fj][r] += __expf(s[fi][fj][r] * SCALEc);
    __syncthreads();  // all reads done -> next stage may overwrite
  }
#pragma unroll
  for (int fi = 0; fi < 2; ++fi)
#pragma unroll
    for (int r = 0; r < 4; ++r) {
      const int n = nt * 128 + wid * 32 + fi * 16 + lg * 4 + r;
      unsigned short* zp = Zpb + (size_t)bs8 * 1048576 +
                           ((size_t)h * 512 + n) * 512 + mt * 128;
#pragma unroll
      for (int fj = 0; fj < 8; ++fj) zp[fj * 16 + lr] = f2bf(zacc[fi][fj][r]);
    }
}

// ---------------------------------------------------------------------------
// Lz = -ln(sum_{8 bf16 partials}). grid 512 x 256, 8 elems/thread.
// Lz stays f32 (consumed by frozen k_av).
// ---------------------------------------------------------------------------
__global__ __launch_bounds__(256) void k_zred(const unsigned short* __restrict__ Zpb,
                                              float* __restrict__ Lz) {
  size_t i = ((size_t)blockIdx.x * 256 + threadIdx.x) * 8;
  float s[8];
#pragma unroll
  for (int j = 0; j < 8; ++j) s[j] = 0.f;
#pragma unroll
  for (int p = 0; p < 8; ++p) {
    u16x8 t = *(const u16x8*)(Zpb + (size_t)p * 1048576 + i);
#pragma unroll
    for (int j = 0; j < 8; ++j) s[j] += bf2f(t[j]);
  }
  float4 o0 = make_float4(-__logf(s[0]), -__logf(s[1]),
                          -__logf(s[2]), -__logf(s[3]));
  float4 o1 = make_float4(-__logf(s[4]), -__logf(s[5]),
                          -__logf(s[6]), -__logf(s[7]));
  *(float4*)(Lz + i) = o0;
  *(float4*)(Lz + i + 4) = o1;
}

// ---------------------------------------------------------------------------
// AV: A[b,h,n,e] = sum_m exp(QK/11 + Lz) * V -> Aw[b,n,h*128+e] bf16.
// grid 1024 flat, XCD-swizzled (h fixed per class). Q in registers;
// K/Vt async dbuf via global_load_lds + XOR; ps XOR-swizzled [128][64]
// => LDS 80KB => 2 blocks/CU. (FROZEN)
// ---------------------------------------------------------------------------
__global__ __launch_bounds__(256, 2) void k_av(
    const unsigned short* __restrict__ Qw, const unsigned short* __restrict__ Kw,
    const unsigned short* __restrict__ Vtw, const float* __restrict__ Lz,
    unsigned short* __restrict__ Aw) {
  __shared__ __align__(16) unsigned short kt[2][64 * 128];
  __shared__ __align__(16) unsigned short vt[2][128 * 64];
  __shared__ __align__(16) unsigned short ps[128 * 64];
  const int tid = threadIdx.x;
  const int bid = blockIdx.x;
  const int c = bid & 7, s_ = bid >> 3;
  const int g = s_ >> 2, nt = s_ & 3;
  const int bh = g * 8 + c;
  const int h = bh & 3, b = bh >> 2;
  const int wid = tid >> 6, lane = tid & 63, lr = lane & 15, lg = lane >> 4;

  const unsigned short* ksrc0 = Kw + (size_t)bh * 65536;
  const unsigned short* vsrc0 = Vtw + (size_t)bh * 65536;
  const unsigned short* qsrc = Qw + ((size_t)bh * 512 + nt * 128) * 128;

  auto stage = [&](int mt, int buf) {
    const unsigned short* kb = ksrc0 + (size_t)mt * 64 * 128;
#pragma unroll
    for (int j = 0; j < 4; ++j) {            // K tile: 64 rows x 256B
      const int cc = wid + 4 * j;
      const int row = 4 * cc + (lane >> 4), sub = lane & 15;
      gl_lds16(kb + row * 128 + ((sub ^ (row & 7)) << 3), &kt[buf][cc * 512]);
    }
    const unsigned short* vb = vsrc0 + mt * 64;
#pragma unroll
    for (int j = 0; j < 4; ++j) {            // Vt tile: 128 rows x 128B
      const int cc = wid + 4 * j;
      const int row = 8 * cc + (lane >> 3), sub = lane & 7;
      gl_lds16(vb + (size_t)row * 512 + ((sub ^ (row & 7)) << 3),
               &vt[buf][cc * 512]);
    }
  };

  stage(0, 0);
  // Q fragments -> registers (wave-private 32 rows)
  bf16x8 qreg[2][4];
#pragma unroll
  for (int pi = 0; pi < 2; ++pi)
#pragma unroll
    for (int ksi = 0; ksi < 4; ++ksi)
      qreg[pi][ksi] = *(const bf16x8*)(qsrc +
          (size_t)(wid * 32 + pi * 16 + lr) * 128 + ksi * 32 + lg * 8);
  __syncthreads();  // buf0 ready

  f32x4 acc[8][2];
#pragma unroll
  for (int i = 0; i < 8; ++i) { acc[i][0] = (f32x4)0.f; acc[i][1] = (f32x4)0.f; }
  const float* zbase = Lz + ((size_t)h * 512 + nt * 128) * 512;

  for (int mt = 0; mt < 8; ++mt) {
    const int cur = mt & 1;
    if (mt < 7) stage(mt + 1, cur ^ 1);
    // Lz for this tile (L2-resident per XCD class)
    float zr[2][4][4];
#pragma unroll
    for (int pi = 0; pi < 2; ++pi)
#pragma unroll
      for (int fm = 0; fm < 4; ++fm)
#pragma unroll
        for (int r = 0; r < 4; ++r)
          zr[pi][fm][r] = zbase[(size_t)(wid * 32 + pi * 16 + lg * 4 + r) * 512 +
                                mt * 64 + fm * 16 + lr];
    // S = Q K^T (32n x 64m per wave)
    f32x4 s[2][4];
#pragma unroll
    for (int i = 0; i < 2; ++i)
#pragma unroll
      for (int j = 0; j < 4; ++j) s[i][j] = (f32x4)0.f;
    __builtin_amdgcn_s_setprio(1);
#pragma unroll
    for (int ksi = 0; ksi < 4; ++ksi) {
      const int k0 = ksi * 32 + lg * 8;
#pragma unroll
      for (int fm = 0; fm < 4; ++fm) {
        const int row = fm * 16 + lr;
        bf16x8 bfr = *(const bf16x8*)&kt[cur][(row * 128 + k0) ^ ((row & 7) << 3)];
        s[0][fm] = MFMA(qreg[0][ksi], bfr, s[0][fm]);
        s[1][fm] = MFMA(qreg[1][ksi], bfr, s[1][fm]);
      }
    }
    __builtin_amdgcn_s_setprio(0);
    // P = exp(s/11 + lz) -> bf16 via cvt_pk -> ps (wave-private rows).
    // ps XOR layout: idx(n,m) = n*64 + (((m>>3)^(n&7))<<3) + (m&7).
#pragma unroll
    for (int pi = 0; pi < 2; ++pi)
#pragma unroll
      for (int fm = 0; fm < 4; ++fm) {
        const int m = fm * 16 + lr;
        const int mhi = (m >> 3), mlo = m & 7;
#pragma unroll
        for (int rp = 0; rp < 4; rp += 2) {
          const float p0 = __expf(fmaf(s[pi][fm][rp], SCALEc, zr[pi][fm][rp]));
          const float p1 = __expf(fmaf(s[pi][fm][rp + 1], SCALEc, zr[pi][fm][rp + 1]));
          unsigned int pk;
          asm("v_cvt_pk_bf16_f32 %0, %1, %2" : "=v"(pk) : "v"(p0), "v"(p1));
          const int n0 = wid * 32 + pi * 16 + lg * 4 + rp;
          ps[n0 * 64 + ((mhi ^ (n0 & 7)) << 3) + mlo] = (unsigned short)pk;
          const int n1 = n0 + 1;
          ps[n1 * 64 + ((mhi ^ (n1 & 7)) << 3) + mlo] = (unsigned short)(pk >> 16);
        }
      }
    // PV: acc[n][e] += P[n][m] * Vt[e][m]
    __builtin_amdgcn_s_setprio(1);
#pragma unroll
    for (int ksm = 0; ksm < 2; ++ksm) {
      const int k0 = ksm * 32 + lg * 8;
      const int kb8 = ksm * 4 + lg;
      const int na0 = wid * 32 + lr, na1 = wid * 32 + 16 + lr;
      bf16x8 pa0 = *(const bf16x8*)&ps[na0 * 64 + ((kb8 ^ (na0 & 7)) << 3)];
      bf16x8 pa1 = *(const bf16x8*)&ps[na1 * 64 + ((kb8 ^ (na1 & 7)) << 3)];
#pragma unroll
      for (int fe = 0; fe < 8; ++fe) {
        const int row = fe * 16 + lr;
        bf16x8 bv_ = *(const bf16x8*)&vt[cur][(row * 64 + k0) ^ ((row & 7) << 3)];
        acc[fe][0] = MFMA(pa0, bv_, acc[fe][0]);
        acc[fe][1] = MFMA(pa1, bv_, acc[fe][1]);
      }
    }
    __builtin_amdgcn_s_setprio(0);
    __syncthreads();  // reads of cur done; next-buf async loads drained
  }
  unsigned short* adst = Aw + ((size_t)(b * 512) + nt * 128) * 512 + h * 128;
#pragma unroll
  for (int pi = 0; pi < 2; ++pi)
#pragma unroll
    for (int r = 0; r < 4; ++r) {
      const int n = wid * 32 + pi * 16 + lg * 4 + r;
#pragma unroll
      for (int fe = 0; fe < 8; ++fe)
        adst[(size_t)n * 512 + fe * 16 + lr] = f2bf(acc[fe][pi][r]);
    }
}

// ---------------------------------------------------------------------------
// Fused MLP: h1 = relu(Acat@W1+b1) kept in LDS (as_ reused);
// out = LN(x + relu(h1@W2+b2))*gamma+beta. grid 256. (FROZEN)
// ---------------------------------------------------------------------------
__global__ __launch_bounds__(256, 2) void k_mlp(
    const unsigned short* __restrict__ Aw, const unsigned short* __restrict__ Wt,
    const float* __restrict__ b1, const float* __restrict__ b2,
    const float* __restrict__ x, const float* __restrict__ gamma,
    const float* __restrict__ beta, float* __restrict__ out) {
  __shared__ unsigned short as_[128][136];
  __shared__ unsigned short w1[128][136];
  const int tid = threadIdx.x;
  const int wid = tid >> 6, lane = tid & 63, lr = lane & 15, lg = lane >> 4;
  const int r0 = blockIdx.x * 128;
  const unsigned short* w1t = Wt + 196608;
  const unsigned short* w2t = Wt + 262144;
  f32x4 acc[2][8];
#pragma unroll
  for (int i = 0; i < 2; ++i)
#pragma unroll
    for (int j = 0; j < 8; ++j) acc[i][j] = (f32x4)0.f;

  // ---- MLP1: Acat[128x512] @ W1t -> acc ----
  for (int ktile = 0; ktile < 4; ++ktile) {
#pragma unroll
    for (int i = 0; i < 8; ++i) {
      int f = tid + i * 256, row = f >> 4, c8 = (f & 15) * 8;
      *(uint4*)&as_[row][c8] =
          *(const uint4*)(Aw + (size_t)(r0 + row) * 512 + ktile * 128 + c8);
      *(uint4*)&w1[row][c8] =
          *(const uint4*)(w1t + (size_t)row * 512 + ktile * 128 + c8);
    }
    __syncthreads();
    __builtin_amdgcn_s_setprio(1);
#pragma unroll
    for (int ksi = 0; ksi < 4; ++ksi) {
      const int k0 = ksi * 32 + lg * 8;
      bf16x8 af0 = *(const bf16x8*)&as_[wid * 32 + lr][k0];
      bf16x8 af1 = *(const bf16x8*)&as_[wid * 32 + 16 + lr][k0];
#pragma unroll
      for (int fj = 0; fj < 8; ++fj) {
        bf16x8 bfr = *(const bf16x8*)&w1[fj * 16 + lr][k0];
        acc[0][fj] = MFMA(af0, bfr, acc[0][fj]);
        acc[1][fj] = MFMA(af1, bfr, acc[1][fj]);
      }
    }
    __builtin_amdgcn_s_setprio(0);
    __syncthreads();  // all reads of as_/w1 done
  }

  // ---- h1 = relu(acc + b1) -> bf16 into as_ ; w2 -> w1 buffer ----
  {
    float bb[8];
#pragma unroll
    for (int fj = 0; fj < 8; ++fj) bb[fj] = b1[fj * 16 + lr];
#pragma unroll
    for (int fi = 0; fi < 2; ++fi)
#pragma unroll
      for (int r = 0; r < 4; ++r) {
        const int row = wid * 32 + fi * 16 + lg * 4 + r;
#pragma unroll
        for (int fj = 0; fj < 8; ++fj)
          as_[row][fj * 16 + lr] = f2bf(fmaxf(acc[fi][fj][r] + bb[fj], 0.f));
      }
#pragma unroll
    for (int i = 0; i < 8; ++i) {
      int f = tid + i * 256, row = f >> 4, c8 = (f & 15) * 8;
      *(uint4*)&w1[row][c8] = *(const uint4*)(w2t + (size_t)row * 128 + c8);
    }
  }
  __syncthreads();  // h1 + w2 visible

  // ---- MLP2: h1[128x128] @ W2t -> out with residual + affine LN ----
#pragma unroll
  for (int i = 0; i < 2; ++i)
#pragma unroll
    for (int j = 0; j < 8; ++j) acc[i][j] = (f32x4)0.f;
  __builtin_amdgcn_s_setprio(1);
#pragma unroll
  for (int ksi = 0; ksi < 4; ++ksi) {
    const int k0 = ksi * 32 + lg * 8;
    bf16x8 af0 = *(const bf16x8*)&as_[wid * 32 + lr][k0];
    bf16x8 af1 = *(const bf16x8*)&as_[wid * 32 + 16 + lr][k0];
#pragma unroll
    for (int fj = 0; fj < 8; ++fj) {
      bf16x8 bfr = *(const bf16x8*)&w1[fj * 16 + lr][k0];
      acc[0][fj] = MFMA(af0, bfr, acc[0][fj]);
      acc[1][fj] = MFMA(af1, bfr, acc[1][fj]);
    }
  }
  __builtin_amdgcn_s_setprio(0);
  float bb[8], gm[8], bt[8];
#pragma unroll
  for (int fj = 0; fj < 8; ++fj) {
    bb[fj] = b2[fj * 16 + lr];
    gm[fj] = gamma[fj * 16 + lr];
    bt[fj] = beta[fj * 16 + lr];
  }
#pragma unroll
  for (int fi = 0; fi < 2; ++fi)
#pragma unroll
    for (int r = 0; r < 4; ++r) {
      const int gr = r0 + wid * 32 + fi * 16 + lg * 4 + r;
      float v[8], s = 0.f, s2 = 0.f;
#pragma unroll
      for (int fj = 0; fj < 8; ++fj) {
        v[fj] = fmaxf(acc[fi][fj][r] + bb[fj], 0.f) +
                x[(size_t)gr * 128 + fj * 16 + lr];
        s += v[fj]; s2 += v[fj] * v[fj];
      }
      s = red16(s); s2 = red16(s2);
      const float mu = s * (1.f / 128.f);
      const float inv = rsqrtf(s2 * (1.f / 128.f) - mu * mu + EPSc);
#pragma unroll
      for (int fj = 0; fj < 8; ++fj)
        out[(size_t)gr * 128 + fj * 16 + lr] =
            (v[fj] - mu) * inv * gm[fj] + bt[fj];
    }
}

extern "C" void kernel_launch(void* const* d_in, const int* in_sizes, int n_in,
                              void* d_out, int out_size, void* d_ws, size_t ws_size,
                              hipStream_t stream) {
  const float* x     = (const float*)d_in[0];
  const float* Wq    = (const float*)d_in[1];
  const float* bq    = (const float*)d_in[2];
  const float* Wk    = (const float*)d_in[3];
  const float* bk    = (const float*)d_in[4];
  const float* Wv    = (const float*)d_in[5];
  const float* bv    = (const float*)d_in[6];
  const float* W1    = (const float*)d_in[7];
  const float* b1    = (const float*)d_in[8];
  const float* W2    = (const float*)d_in[9];
  const float* b2    = (const float*)d_in[10];
  const float* gamma = (const float*)d_in[11];
  const float* beta  = (const float*)d_in[12];
  float* out = (float*)d_out;

  // ws layout: xb 8MB | Qw 33.5MB | Kw 33.5MB | Vtw 33.5MB |
  // ZpA 33.5MB (Zpb bf16 16.7MB -> later Aw bf16) | Lz 4MB | Wts 0.6MB
  unsigned short* xb  = (unsigned short*)d_ws;
  unsigned short* Qw  = xb + 4194304;
  unsigned short* Kw  = Qw + 16777216;
  unsigned short* Vtw = Kw + 16777216;
  unsigned short* ZpA = Vtw + 16777216;
  unsigned short* Zpb = ZpA;      // 8 x 1,048,576 bf16 = 16.7MB
  unsigned short* Aw = ZpA;       // alias: Zpb dead after k_zred
  float* Lz = (float*)(ZpA + 16777216);
  unsigned short* Wts = (unsigned short*)(Lz + 1048576);

  k_conv <<<3136, 256, 0, stream>>>(x, Wq, Wk, Wv, W1, W2, xb, Wts);
  k_proj <<<dim3(256, 8), 256, 0, stream>>>(xb, Wts, bq, bk, bv, Qw, Kw, Vtw);
  k_z    <<<512, 256, 0, stream>>>(Qw, Kw, Zpb);
  k_zred <<<512, 256, 0, stream>>>(Zpb, Lz);
  k_av   <<<1024, 256, 0, stream>>>(Qw, Kw, Vtw, Lz, Aw);
  k_mlp  <<<256, 256, 0, stream>>>(Aw, Wts, b1, b2, x, gamma, beta, out);
}

// Round 19
// 159.995 us; speedup vs baseline: 1.1006x; 1.0069x over previous
//
#include <hip/hip_runtime.h>
#include <hip/hip_bf16.h>

// ---------------------------------------------------------------------------
// Round 18 = R17 (passing, 161.1us) + V folded into the Q/K projection
// blocks as a THIRD phase (stage-once/multi-phase pattern, proven in k_mlp
// and the R16 Q+K fusion). Grid (256,8) -> (256,4); xs staged once per tile
// for Q, K, AND V; wt reloaded between phases with epilogue overlap.
// k_conv / k_z / k_zred / k_av / k_mlp byte-exact R17 (FROZEN core).
// ---------------------------------------------------------------------------

typedef __bf16 bf16x8 __attribute__((ext_vector_type(8)));
typedef unsigned short u16x8 __attribute__((ext_vector_type(8)));
typedef float f32x4 __attribute__((ext_vector_type(4)));

constexpr float SCALEc = 1.0f / 11.0f;  // int(sqrt(128)) == 11 (faithful)
constexpr float EPSc = 1e-5f;

#define MFMA(a, b, c) __builtin_amdgcn_mfma_f32_16x16x32_bf16(a, b, c, 0, 0, 0)

static __device__ __forceinline__ unsigned short f2bf(float f) {
  unsigned int x = __float_as_uint(f);
  x += 0x7fffu + ((x >> 16) & 1u);  // RNE
  return (unsigned short)(x >> 16);
}
static __device__ __forceinline__ float bf2f(unsigned short u) {
  return __uint_as_float(((unsigned int)u) << 16);
}
static __device__ __forceinline__ unsigned int pack2(float a, float b) {
  return (unsigned int)f2bf(a) | ((unsigned int)f2bf(b) << 16);
}
static __device__ __forceinline__ float red16(float v) {
  v += __shfl_xor(v, 1); v += __shfl_xor(v, 2);
  v += __shfl_xor(v, 4); v += __shfl_xor(v, 8);
  return v;
}
// async 16B global->LDS (LDS dest = wave-uniform base + lane*16, linear)
static __device__ __forceinline__ void gl_lds16(const void* g, void* l) {
  __builtin_amdgcn_global_load_lds(
      (const __attribute__((address_space(1))) void*)g,
      (__attribute__((address_space(3))) void*)l, 16, 0, 0);
}

// ---------------------------------------------------------------------------
// Fused converts: blocks [0,2048) -> xb = bf16(x); [2048,3136) -> Wt.
// ---------------------------------------------------------------------------
__global__ __launch_bounds__(256) void k_conv(
    const float* __restrict__ x, const float* __restrict__ Wq,
    const float* __restrict__ Wk, const float* __restrict__ Wv,
    const float* __restrict__ W1, const float* __restrict__ W2,
    unsigned short* __restrict__ xb, unsigned short* __restrict__ Wt) {
  const int bid = blockIdx.x;
  if (bid < 2048) {
    size_t i = ((size_t)bid * 256 + threadIdx.x) * 8;
    float4 a = *(const float4*)(x + i);
    float4 b = *(const float4*)(x + i + 4);
    uint4 o;
    o.x = pack2(a.x, a.y); o.y = pack2(a.z, a.w);
    o.z = pack2(b.x, b.y); o.w = pack2(b.z, b.w);
    *(uint4*)(xb + i) = o;
    return;
  }
  int t = (bid - 2048) * 256 + threadIdx.x;
  if (t < 196608) {
    int which = t >> 16, r = t & 65535;
    int h = r >> 14, idx = r & 16383;
    int d = idx >> 7, e = idx & 127;
    const float* W = which == 0 ? Wq : (which == 1 ? Wk : Wv);
    Wt[t] = f2bf(W[h * 16384 + e * 128 + d]);
  } else if (t < 262144) {
    int r = t - 196608, d = r >> 9, k = r & 511;
    Wt[t] = f2bf(W1[k * 128 + d]);
  } else if (t < 278528) {
    int r = t - 262144, d = r >> 7, k = r & 127;
    Wt[t] = f2bf(W2[k * 128 + d]);
  }
}

// ---------------------------------------------------------------------------
// Fused projections. grid (256, 4): per (tile, h) block stages xs ONCE and
// runs Q, K, V phases (wt reloaded between phases; epilogues overlap loads).
// ---------------------------------------------------------------------------
__global__ __launch_bounds__(256, 2) void k_proj(
    const unsigned short* __restrict__ xb, const unsigned short* __restrict__ Wt,
    const float* __restrict__ bq, const float* __restrict__ bk,
    const float* __restrict__ bv, unsigned short* __restrict__ Qw,
    unsigned short* __restrict__ Kw, unsigned short* __restrict__ Vtw) {
  __shared__ unsigned short xs[128][136];
  __shared__ unsigned short wt[128][136];
  const int tid = threadIdx.x;
  const int wid = tid >> 6, lane = tid & 63, lr = lane & 15, lg = lane >> 4;

  const int h = blockIdx.y;
  const int r0 = blockIdx.x * 128;
  const unsigned short* wsrcQ = Wt + h * 16384;            // proj 0
  const unsigned short* wsrcK = Wt + 65536 + h * 16384;    // proj 1
  const unsigned short* wsrcV = Wt + 131072 + h * 16384;   // proj 2
  const size_t drow = ((size_t)((r0 >> 9) * 4 + h) * 512 + (r0 & 511)) * 128;
  unsigned short* dstQ = Qw + drow;
  unsigned short* dstK = Kw + drow;
  const int wr0 = wid * 32;

  // stage xs (once) + Wq
#pragma unroll
  for (int i = 0; i < 8; ++i) {
    int f = tid + i * 256, row = f >> 4, c8 = (f & 15) * 8;
    *(uint4*)&xs[row][c8] = *(const uint4*)(xb + (size_t)(r0 + row) * 128 + c8);
    *(uint4*)&wt[row][c8] = *(const uint4*)(wsrcQ + row * 128 + c8);
  }
  __syncthreads();

  // ---- Q phase ----
  f32x4 acc[2][8];
#pragma unroll
  for (int i = 0; i < 2; ++i)
#pragma unroll
    for (int j = 0; j < 8; ++j) acc[i][j] = (f32x4)0.f;
  __builtin_amdgcn_s_setprio(1);
#pragma unroll
  for (int ksi = 0; ksi < 4; ++ksi) {
    const int k0 = ksi * 32 + lg * 8;
    bf16x8 af0 = *(const bf16x8*)&xs[wr0 + lr][k0];
    bf16x8 af1 = *(const bf16x8*)&xs[wr0 + 16 + lr][k0];
#pragma unroll
    for (int fj = 0; fj < 8; ++fj) {
      bf16x8 bfr = *(const bf16x8*)&wt[fj * 16 + lr][k0];
      acc[0][fj] = MFMA(af0, bfr, acc[0][fj]);
      acc[1][fj] = MFMA(af1, bfr, acc[1][fj]);
    }
  }
  __builtin_amdgcn_s_setprio(0);
  __syncthreads();  // all wt reads done -> safe to overwrite with Wk

  // issue Wk loads; Q epilogue overlaps them
#pragma unroll
  for (int i = 0; i < 8; ++i) {
    int f = tid + i * 256, row = f >> 4, c8 = (f & 15) * 8;
    *(uint4*)&wt[row][c8] = *(const uint4*)(wsrcK + row * 128 + c8);
  }
  {
    float bb[8];
#pragma unroll
    for (int fj = 0; fj < 8; ++fj) bb[fj] = bq[h * 128 + fj * 16 + lr];
#pragma unroll
    for (int fi = 0; fi < 2; ++fi)
#pragma unroll
      for (int r = 0; r < 4; ++r) {
        const int row = wr0 + fi * 16 + lg * 4 + r;
        float v[8], s = 0.f, s2 = 0.f;
#pragma unroll
        for (int fj = 0; fj < 8; ++fj) {
          v[fj] = acc[fi][fj][r] + bb[fj];
          s += v[fj]; s2 += v[fj] * v[fj];
        }
        s = red16(s); s2 = red16(s2);
        const float mu = s * (1.f / 128.f);
        const float inv = rsqrtf(s2 * (1.f / 128.f) - mu * mu + EPSc);
#pragma unroll
        for (int fj = 0; fj < 8; ++fj)
          dstQ[(size_t)row * 128 + fj * 16 + lr] = f2bf((v[fj] - mu) * inv);
      }
  }
  __syncthreads();  // Wk visible

  // ---- K phase ----
#pragma unroll
  for (int i = 0; i < 2; ++i)
#pragma unroll
    for (int j = 0; j < 8; ++j) acc[i][j] = (f32x4)0.f;
  __builtin_amdgcn_s_setprio(1);
#pragma unroll
  for (int ksi = 0; ksi < 4; ++ksi) {
    const int k0 = ksi * 32 + lg * 8;
    bf16x8 af0 = *(const bf16x8*)&xs[wr0 + lr][k0];
    bf16x8 af1 = *(const bf16x8*)&xs[wr0 + 16 + lr][k0];
#pragma unroll
    for (int fj = 0; fj < 8; ++fj) {
      bf16x8 bfr = *(const bf16x8*)&wt[fj * 16 + lr][k0];
      acc[0][fj] = MFMA(af0, bfr, acc[0][fj]);
      acc[1][fj] = MFMA(af1, bfr, acc[1][fj]);
    }
  }
  __builtin_amdgcn_s_setprio(0);
  __syncthreads();  // all wt reads done -> safe to overwrite with Wv

  // issue Wv loads; K epilogue overlaps them
#pragma unroll
  for (int i = 0; i < 8; ++i) {
    int f = tid + i * 256, row = f >> 4, c8 = (f & 15) * 8;
    *(uint4*)&wt[row][c8] = *(const uint4*)(wsrcV + row * 128 + c8);
  }
  {
    float bb[8];
#pragma unroll
    for (int fj = 0; fj < 8; ++fj) bb[fj] = bk[h * 128 + fj * 16 + lr];
#pragma unroll
    for (int fi = 0; fi < 2; ++fi)
#pragma unroll
      for (int r = 0; r < 4; ++r) {
        const int row = wr0 + fi * 16 + lg * 4 + r;
        float v[8], s = 0.f, s2 = 0.f;
#pragma unroll
        for (int fj = 0; fj < 8; ++fj) {
          v[fj] = acc[fi][fj][r] + bb[fj];
          s += v[fj]; s2 += v[fj] * v[fj];
        }
        s = red16(s); s2 = red16(s2);
        const float mu = s * (1.f / 128.f);
        const float inv = rsqrtf(s2 * (1.f / 128.f) - mu * mu + EPSc);
#pragma unroll
        for (int fj = 0; fj < 8; ++fj)
          dstK[(size_t)row * 128 + fj * 16 + lr] = f2bf((v[fj] - mu) * inv);
      }
  }
  __syncthreads();  // Wv visible

  // ---- V phase (transposed output, cross-lane LN; R17 body, n0 = r0) ----
  const int n0 = r0;
  const int wn0 = wid * 32;
  f32x4 vacc[8][2];
#pragma unroll
  for (int i = 0; i < 8; ++i) {
    vacc[i][0] = (f32x4)0.f; vacc[i][1] = (f32x4)0.f;
  }
  __builtin_amdgcn_s_setprio(1);
#pragma unroll
  for (int ksi = 0; ksi < 4; ++ksi) {
    const int k0 = ksi * 32 + lg * 8;
    bf16x8 bf0 = *(const bf16x8*)&xs[wn0 + lr][k0];
    bf16x8 bf1 = *(const bf16x8*)&xs[wn0 + 16 + lr][k0];
#pragma unroll
    for (int fi = 0; fi < 8; ++fi) {
      bf16x8 af = *(const bf16x8*)&wt[fi * 16 + lr][k0];
      vacc[fi][0] = MFMA(af, bf0, vacc[fi][0]);
      vacc[fi][1] = MFMA(af, bf1, vacc[fi][1]);
    }
  }
  __builtin_amdgcn_s_setprio(0);
#pragma unroll
  for (int fi = 0; fi < 8; ++fi)
#pragma unroll
    for (int r = 0; r < 4; ++r) {
      const float bvv = bv[h * 128 + fi * 16 + lg * 4 + r];
      vacc[fi][0][r] += bvv; vacc[fi][1][r] += bvv;
    }
  const int gb = n0 >> 9;
  unsigned short* base = Vtw + (size_t)(gb * 4 + h) * 128 * 512;
#pragma unroll
  for (int fj = 0; fj < 2; ++fj) {
    float s = 0.f, s2 = 0.f;
#pragma unroll
    for (int fi = 0; fi < 8; ++fi)
#pragma unroll
      for (int r = 0; r < 4; ++r) {
        const float v = vacc[fi][fj][r];
        s += v; s2 += v * v;
      }
    s += __shfl_xor(s, 16); s += __shfl_xor(s, 32);
    s2 += __shfl_xor(s2, 16); s2 += __shfl_xor(s2, 32);
    const float mu = s * (1.f / 128.f);
    const float inv = rsqrtf(s2 * (1.f / 128.f) - mu * mu + EPSc);
    const int nl = (n0 & 511) + wn0 + fj * 16 + lr;
#pragma unroll
    for (int fi = 0; fi < 8; ++fi)
#pragma unroll
      for (int r = 0; r < 4; ++r) {
        const int eout = fi * 16 + lg * 4 + r;
        base[(size_t)eout * 512 + nl] = f2bf((vacc[fi][fj][r] - mu) * inv);
      }
  }
}

// ---------------------------------------------------------------------------
// Z partials: Zpb = bf16(sum_{8 b} exp(QK/11)). grid 512 flat. (FROZEN)
// ---------------------------------------------------------------------------
__global__ __launch_bounds__(256, 2) void k_z(
    const unsigned short* __restrict__ Qw, const unsigned short* __restrict__ Kw,
    unsigned short* __restrict__ Zpb) {
  __shared__ __align__(16) unsigned short qs[128 * 128];
  __shared__ __align__(16) unsigned short ks_[128 * 128];
  const int tid = threadIdx.x;
  const int bid = blockIdx.x;
  const int c = bid & 7, s_ = bid >> 3;          // XCD class, sequence [0,64)
  const int combo = (s_ >> 4) * 8 + c;           // [0,32)
  const int h = combo & 3, bs8 = combo >> 2;     // h fixed per class
  const int t = s_ & 15;
  const int nt = t >> 2, mt = t & 3;
  const int wid = tid >> 6, lane = tid & 63, lr = lane & 15, lg = lane >> 4;
  const int srow = lane >> 4, ssub = lane & 15;  // staging role

  auto stageZ = [&](const unsigned short* qb, const unsigned short* kb) {
#pragma unroll
    for (int j = 0; j < 8; ++j) {
      const int cc = wid + 4 * j;                // 1KB chunk = 4 rows of 256B
      const int row = 4 * cc + srow;
      const int gof = row * 128 + ((ssub ^ (row & 7)) << 3);
      gl_lds16(qb + gof, &qs[cc * 512]);
      gl_lds16(kb + gof, &ks_[cc * 512]);
    }
  };

  f32x4 zacc[2][8];
#pragma unroll
  for (int i = 0; i < 2; ++i)
#pragma unroll
    for (int j = 0; j < 8; ++j) zacc[i][j] = (f32x4)0.f;

  const int b0 = bs8 * 8;
  for (int bi = 0; bi < 8; ++bi) {
    const int b = b0 + bi;
    stageZ(Qw + ((size_t)(b * 4 + h) * 512 + nt * 128) * 128,
           Kw + ((size_t)(b * 4 + h) * 512 + mt * 128) * 128);
    __syncthreads();  // vmcnt(0) drain: tiles ready
    f32x4 s[2][8];
#pragma unroll
    for (int i = 0; i < 2; ++i)
#pragma unroll
      for (int j = 0; j < 8; ++j) s[i][j] = (f32x4)0.f;
    __builtin_amdgcn_s_setprio(1);
#pragma unroll
    for (int ksi = 0; ksi < 4; ++ksi) {
      const int k0 = ksi * 32 + lg * 8;
      const int ra0 = wid * 32 + lr, ra1 = wid * 32 + 16 + lr;
      bf16x8 af0 = *(const bf16x8*)&qs[(ra0 * 128 + k0) ^ ((ra0 & 7) << 3)];
      bf16x8 af1 = *(const bf16x8*)&qs[(ra1 * 128 + k0) ^ ((ra1 & 7) << 3)];
#pragma unroll
      for (int fj = 0; fj < 8; ++fj) {
        const int rb = fj * 16 + lr;
        bf16x8 bfr = *(const bf16x8*)&ks_[(rb * 128 + k0) ^ ((rb & 7) << 3)];
        s[0][fj] = MFMA(af0, bfr, s[0][fj]);
        s[1][fj] = MFMA(af1, bfr, s[1][fj]);
      }
    }
    __builtin_amdgcn_s_setprio(0);
#pragma unroll
    for (int fi = 0; fi < 2; ++fi)
#pragma unroll
      for (int fj = 0; fj < 8; ++fj)
#pragma unroll
        for (int r = 0; r < 4; ++r)
          zacc[fi][fj][r] += __expf(s[fi][fj][r] * SCALEc);
    __syncthreads();  // all reads done -> next stage may overwrite
  }
#pragma unroll
  for (int fi = 0; fi < 2; ++fi)
#pragma unroll
    for (int r = 0; r < 4; ++r) {
      const int n = nt * 128 + wid * 32 + fi * 16 + lg * 4 + r;
      unsigned short* zp = Zpb + (size_t)bs8 * 1048576 +
                           ((size_t)h * 512 + n) * 512 + mt * 128;
#pragma unroll
      for (int fj = 0; fj < 8; ++fj) zp[fj * 16 + lr] = f2bf(zacc[fi][fj][r]);
    }
}

// ---------------------------------------------------------------------------
// Lz = -ln(sum_{8 bf16 partials}). grid 512 x 256. (FROZEN)
// ---------------------------------------------------------------------------
__global__ __launch_bounds__(256) void k_zred(const unsigned short* __restrict__ Zpb,
                                              float* __restrict__ Lz) {
  size_t i = ((size_t)blockIdx.x * 256 + threadIdx.x) * 8;
  float s[8];
#pragma unroll
  for (int j = 0; j < 8; ++j) s[j] = 0.f;
#pragma unroll
  for (int p = 0; p < 8; ++p) {
    u16x8 t = *(const u16x8*)(Zpb + (size_t)p * 1048576 + i);
#pragma unroll
    for (int j = 0; j < 8; ++j) s[j] += bf2f(t[j]);
  }
  float4 o0 = make_float4(-__logf(s[0]), -__logf(s[1]),
                          -__logf(s[2]), -__logf(s[3]));
  float4 o1 = make_float4(-__logf(s[4]), -__logf(s[5]),
                          -__logf(s[6]), -__logf(s[7]));
  *(float4*)(Lz + i) = o0;
  *(float4*)(Lz + i + 4) = o1;
}

// ---------------------------------------------------------------------------
// AV: A[b,h,n,e] = sum_m exp(QK/11 + Lz) * V -> Aw[b,n,h*128+e] bf16.
// (FROZEN)
// ---------------------------------------------------------------------------
__global__ __launch_bounds__(256, 2) void k_av(
    const unsigned short* __restrict__ Qw, const unsigned short* __restrict__ Kw,
    const unsigned short* __restrict__ Vtw, const float* __restrict__ Lz,
    unsigned short* __restrict__ Aw) {
  __shared__ __align__(16) unsigned short kt[2][64 * 128];
  __shared__ __align__(16) unsigned short vt[2][128 * 64];
  __shared__ __align__(16) unsigned short ps[128 * 64];
  const int tid = threadIdx.x;
  const int bid = blockIdx.x;
  const int c = bid & 7, s_ = bid >> 3;
  const int g = s_ >> 2, nt = s_ & 3;
  const int bh = g * 8 + c;
  const int h = bh & 3, b = bh >> 2;
  const int wid = tid >> 6, lane = tid & 63, lr = lane & 15, lg = lane >> 4;

  const unsigned short* ksrc0 = Kw + (size_t)bh * 65536;
  const unsigned short* vsrc0 = Vtw + (size_t)bh * 65536;
  const unsigned short* qsrc = Qw + ((size_t)bh * 512 + nt * 128) * 128;

  auto stage = [&](int mt, int buf) {
    const unsigned short* kb = ksrc0 + (size_t)mt * 64 * 128;
#pragma unroll
    for (int j = 0; j < 4; ++j) {            // K tile: 64 rows x 256B
      const int cc = wid + 4 * j;
      const int row = 4 * cc + (lane >> 4), sub = lane & 15;
      gl_lds16(kb + row * 128 + ((sub ^ (row & 7)) << 3), &kt[buf][cc * 512]);
    }
    const unsigned short* vb = vsrc0 + mt * 64;
#pragma unroll
    for (int j = 0; j < 4; ++j) {            // Vt tile: 128 rows x 128B
      const int cc = wid + 4 * j;
      const int row = 8 * cc + (lane >> 3), sub = lane & 7;
      gl_lds16(vb + (size_t)row * 512 + ((sub ^ (row & 7)) << 3),
               &vt[buf][cc * 512]);
    }
  };

  stage(0, 0);
  // Q fragments -> registers (wave-private 32 rows)
  bf16x8 qreg[2][4];
#pragma unroll
  for (int pi = 0; pi < 2; ++pi)
#pragma unroll
    for (int ksi = 0; ksi < 4; ++ksi)
      qreg[pi][ksi] = *(const bf16x8*)(qsrc +
          (size_t)(wid * 32 + pi * 16 + lr) * 128 + ksi * 32 + lg * 8);
  __syncthreads();  // buf0 ready

  f32x4 acc[8][2];
#pragma unroll
  for (int i = 0; i < 8; ++i) { acc[i][0] = (f32x4)0.f; acc[i][1] = (f32x4)0.f; }
  const float* zbase = Lz + ((size_t)h * 512 + nt * 128) * 512;

  for (int mt = 0; mt < 8; ++mt) {
    const int cur = mt & 1;
    if (mt < 7) stage(mt + 1, cur ^ 1);
    // Lz for this tile (L2-resident per XCD class)
    float zr[2][4][4];
#pragma unroll
    for (int pi = 0; pi < 2; ++pi)
#pragma unroll
      for (int fm = 0; fm < 4; ++fm)
#pragma unroll
        for (int r = 0; r < 4; ++r)
          zr[pi][fm][r] = zbase[(size_t)(wid * 32 + pi * 16 + lg * 4 + r) * 512 +
                                mt * 64 + fm * 16 + lr];
    // S = Q K^T (32n x 64m per wave)
    f32x4 s[2][4];
#pragma unroll
    for (int i = 0; i < 2; ++i)
#pragma unroll
      for (int j = 0; j < 4; ++j) s[i][j] = (f32x4)0.f;
    __builtin_amdgcn_s_setprio(1);
#pragma unroll
    for (int ksi = 0; ksi < 4; ++ksi) {
      const int k0 = ksi * 32 + lg * 8;
#pragma unroll
      for (int fm = 0; fm < 4; ++fm) {
        const int row = fm * 16 + lr;
        bf16x8 bfr = *(const bf16x8*)&kt[cur][(row * 128 + k0) ^ ((row & 7) << 3)];
        s[0][fm] = MFMA(qreg[0][ksi], bfr, s[0][fm]);
        s[1][fm] = MFMA(qreg[1][ksi], bfr, s[1][fm]);
      }
    }
    __builtin_amdgcn_s_setprio(0);
    // P = exp(s/11 + lz) -> bf16 via cvt_pk -> ps (wave-private rows).
    // ps XOR layout: idx(n,m) = n*64 + (((m>>3)^(n&7))<<3) + (m&7).
#pragma unroll
    for (int pi = 0; pi < 2; ++pi)
#pragma unroll
      for (int fm = 0; fm < 4; ++fm) {
        const int m = fm * 16 + lr;
        const int mhi = (m >> 3), mlo = m & 7;
#pragma unroll
        for (int rp = 0; rp < 4; rp += 2) {
          const float p0 = __expf(fmaf(s[pi][fm][rp], SCALEc, zr[pi][fm][rp]));
          const float p1 = __expf(fmaf(s[pi][fm][rp + 1], SCALEc, zr[pi][fm][rp + 1]));
          unsigned int pk;
          asm("v_cvt_pk_bf16_f32 %0, %1, %2" : "=v"(pk) : "v"(p0), "v"(p1));
          const int n0 = wid * 32 + pi * 16 + lg * 4 + rp;
          ps[n0 * 64 + ((mhi ^ (n0 & 7)) << 3) + mlo] = (unsigned short)pk;
          const int n1 = n0 + 1;
          ps[n1 * 64 + ((mhi ^ (n1 & 7)) << 3) + mlo] = (unsigned short)(pk >> 16);
        }
      }
    // PV: acc[n][e] += P[n][m] * Vt[e][m]
    __builtin_amdgcn_s_setprio(1);
#pragma unroll
    for (int ksm = 0; ksm < 2; ++ksm) {
      const int k0 = ksm * 32 + lg * 8;
      const int kb8 = ksm * 4 + lg;
      const int na0 = wid * 32 + lr, na1 = wid * 32 + 16 + lr;
      bf16x8 pa0 = *(const bf16x8*)&ps[na0 * 64 + ((kb8 ^ (na0 & 7)) << 3)];
      bf16x8 pa1 = *(const bf16x8*)&ps[na1 * 64 + ((kb8 ^ (na1 & 7)) << 3)];
#pragma unroll
      for (int fe = 0; fe < 8; ++fe) {
        const int row = fe * 16 + lr;
        bf16x8 bv_ = *(const bf16x8*)&vt[cur][(row * 64 + k0) ^ ((row & 7) << 3)];
        acc[fe][0] = MFMA(pa0, bv_, acc[fe][0]);
        acc[fe][1] = MFMA(pa1, bv_, acc[fe][1]);
      }
    }
    __builtin_amdgcn_s_setprio(0);
    __syncthreads();  // reads of cur done; next-buf async loads drained
  }
  unsigned short* adst = Aw + ((size_t)(b * 512) + nt * 128) * 512 + h * 128;
#pragma unroll
  for (int pi = 0; pi < 2; ++pi)
#pragma unroll
    for (int r = 0; r < 4; ++r) {
      const int n = wid * 32 + pi * 16 + lg * 4 + r;
#pragma unroll
      for (int fe = 0; fe < 8; ++fe)
        adst[(size_t)n * 512 + fe * 16 + lr] = f2bf(acc[fe][pi][r]);
    }
}

// ---------------------------------------------------------------------------
// Fused MLP: h1 = relu(Acat@W1+b1) kept in LDS (as_ reused);
// out = LN(x + relu(h1@W2+b2))*gamma+beta. grid 256. (FROZEN)
// ---------------------------------------------------------------------------
__global__ __launch_bounds__(256, 2) void k_mlp(
    const unsigned short* __restrict__ Aw, const unsigned short* __restrict__ Wt,
    const float* __restrict__ b1, const float* __restrict__ b2,
    const float* __restrict__ x, const float* __restrict__ gamma,
    const float* __restrict__ beta, float* __restrict__ out) {
  __shared__ unsigned short as_[128][136];
  __shared__ unsigned short w1[128][136];
  const int tid = threadIdx.x;
  const int wid = tid >> 6, lane = tid & 63, lr = lane & 15, lg = lane >> 4;
  const int r0 = blockIdx.x * 128;
  const unsigned short* w1t = Wt + 196608;
  const unsigned short* w2t = Wt + 262144;
  f32x4 acc[2][8];
#pragma unroll
  for (int i = 0; i < 2; ++i)
#pragma unroll
    for (int j = 0; j < 8; ++j) acc[i][j] = (f32x4)0.f;

  // ---- MLP1: Acat[128x512] @ W1t -> acc ----
  for (int ktile = 0; ktile < 4; ++ktile) {
#pragma unroll
    for (int i = 0; i < 8; ++i) {
      int f = tid + i * 256, row = f >> 4, c8 = (f & 15) * 8;
      *(uint4*)&as_[row][c8] =
          *(const uint4*)(Aw + (size_t)(r0 + row) * 512 + ktile * 128 + c8);
      *(uint4*)&w1[row][c8] =
          *(const uint4*)(w1t + (size_t)row * 512 + ktile * 128 + c8);
    }
    __syncthreads();
    __builtin_amdgcn_s_setprio(1);
#pragma unroll
    for (int ksi = 0; ksi < 4; ++ksi) {
      const int k0 = ksi * 32 + lg * 8;
      bf16x8 af0 = *(const bf16x8*)&as_[wid * 32 + lr][k0];
      bf16x8 af1 = *(const bf16x8*)&as_[wid * 32 + 16 + lr][k0];
#pragma unroll
      for (int fj = 0; fj < 8; ++fj) {
        bf16x8 bfr = *(const bf16x8*)&w1[fj * 16 + lr][k0];
        acc[0][fj] = MFMA(af0, bfr, acc[0][fj]);
        acc[1][fj] = MFMA(af1, bfr, acc[1][fj]);
      }
    }
    __builtin_amdgcn_s_setprio(0);
    __syncthreads();  // all reads of as_/w1 done
  }

  // ---- h1 = relu(acc + b1) -> bf16 into as_ ; w2 -> w1 buffer ----
  {
    float bb[8];
#pragma unroll
    for (int fj = 0; fj < 8; ++fj) bb[fj] = b1[fj * 16 + lr];
#pragma unroll
    for (int fi = 0; fi < 2; ++fi)
#pragma unroll
      for (int r = 0; r < 4; ++r) {
        const int row = wid * 32 + fi * 16 + lg * 4 + r;
#pragma unroll
        for (int fj = 0; fj < 8; ++fj)
          as_[row][fj * 16 + lr] = f2bf(fmaxf(acc[fi][fj][r] + bb[fj], 0.f));
      }
#pragma unroll
    for (int i = 0; i < 8; ++i) {
      int f = tid + i * 256, row = f >> 4, c8 = (f & 15) * 8;
      *(uint4*)&w1[row][c8] = *(const uint4*)(w2t + (size_t)row * 128 + c8);
    }
  }
  __syncthreads();  // h1 + w2 visible

  // ---- MLP2: h1[128x128] @ W2t -> out with residual + affine LN ----
#pragma unroll
  for (int i = 0; i < 2; ++i)
#pragma unroll
    for (int j = 0; j < 8; ++j) acc[i][j] = (f32x4)0.f;
  __builtin_amdgcn_s_setprio(1);
#pragma unroll
  for (int ksi = 0; ksi < 4; ++ksi) {
    const int k0 = ksi * 32 + lg * 8;
    bf16x8 af0 = *(const bf16x8*)&as_[wid * 32 + lr][k0];
    bf16x8 af1 = *(const bf16x8*)&as_[wid * 32 + 16 + lr][k0];
#pragma unroll
    for (int fj = 0; fj < 8; ++fj) {
      bf16x8 bfr = *(const bf16x8*)&w1[fj * 16 + lr][k0];
      acc[0][fj] = MFMA(af0, bfr, acc[0][fj]);
      acc[1][fj] = MFMA(af1, bfr, acc[1][fj]);
    }
  }
  __builtin_amdgcn_s_setprio(0);
  float bb[8], gm[8], bt[8];
#pragma unroll
  for (int fj = 0; fj < 8; ++fj) {
    bb[fj] = b2[fj * 16 + lr];
    gm[fj] = gamma[fj * 16 + lr];
    bt[fj] = beta[fj * 16 + lr];
  }
#pragma unroll
  for (int fi = 0; fi < 2; ++fi)
#pragma unroll
    for (int r = 0; r < 4; ++r) {
      const int gr = r0 + wid * 32 + fi * 16 + lg * 4 + r;
      float v[8], s = 0.f, s2 = 0.f;
#pragma unroll
      for (int fj = 0; fj < 8; ++fj) {
        v[fj] = fmaxf(acc[fi][fj][r] + bb[fj], 0.f) +
                x[(size_t)gr * 128 + fj * 16 + lr];
        s += v[fj]; s2 += v[fj] * v[fj];
      }
      s = red16(s); s2 = red16(s2);
      const float mu = s * (1.f / 128.f);
      const float inv = rsqrtf(s2 * (1.f / 128.f) - mu * mu + EPSc);
#pragma unroll
      for (int fj = 0; fj < 8; ++fj)
        out[(size_t)gr * 128 + fj * 16 + lr] =
            (v[fj] - mu) * inv * gm[fj] + bt[fj];
    }
}

extern "C" void kernel_launch(void* const* d_in, const int* in_sizes, int n_in,
                              void* d_out, int out_size, void* d_ws, size_t ws_size,
                              hipStream_t stream) {
  const float* x     = (const float*)d_in[0];
  const float* Wq    = (const float*)d_in[1];
  const float* bq    = (const float*)d_in[2];
  const float* Wk    = (const float*)d_in[3];
  const float* bk    = (const float*)d_in[4];
  const float* Wv    = (const float*)d_in[5];
  const float* bv    = (const float*)d_in[6];
  const float* W1    = (const float*)d_in[7];
  const float* b1    = (const float*)d_in[8];
  const float* W2    = (const float*)d_in[9];
  const float* b2    = (const float*)d_in[10];
  const float* gamma = (const float*)d_in[11];
  const float* beta  = (const float*)d_in[12];
  float* out = (float*)d_out;

  // ws layout: xb 8MB | Qw 33.5MB | Kw 33.5MB | Vtw 33.5MB |
  // ZpA 33.5MB (Zpb bf16 16.7MB -> later Aw bf16) | Lz 4MB | Wts 0.6MB
  unsigned short* xb  = (unsigned short*)d_ws;
  unsigned short* Qw  = xb + 4194304;
  unsigned short* Kw  = Qw + 16777216;
  unsigned short* Vtw = Kw + 16777216;
  unsigned short* ZpA = Vtw + 16777216;
  unsigned short* Zpb = ZpA;      // 8 x 1,048,576 bf16 = 16.7MB
  unsigned short* Aw = ZpA;       // alias: Zpb dead after k_zred
  float* Lz = (float*)(ZpA + 16777216);
  unsigned short* Wts = (unsigned short*)(Lz + 1048576);

  k_conv <<<3136, 256, 0, stream>>>(x, Wq, Wk, Wv, W1, W2, xb, Wts);
  k_proj <<<dim3(256, 4), 256, 0, stream>>>(xb, Wts, bq, bk, bv, Qw, Kw, Vtw);
  k_z    <<<512, 256, 0, stream>>>(Qw, Kw, Zpb);
  k_zred <<<512, 256, 0, stream>>>(Zpb, Lz);
  k_av   <<<1024, 256, 0, stream>>>(Qw, Kw, Vtw, Lz, Aw);
  k_mlp  <<<256, 256, 0, stream>>>(Aw, Wts, b1, b2, x, gamma, beta, out);
}